// Round 1
// 752.671 us; speedup vs baseline: 1.1357x; 1.1357x over previous
//
#include <hip/hip_runtime.h>
#include <cstdint>

// Problem constants (B, LQ, LK, D fixed by the reference)
#define DDIM 1024
#define LQN  2048
#define LKN  2048
#define BBAT 8

// ROUND-4 PLAN: all-bf16 GEMMs + global_load_lds staging (m97 structure).
//  - cast query/key/W* to bf16 up-front (one vectorized pass)
//  - softmax writes BOTH f32 P (required output) and bf16 Pb (feeds O-GEMM)
//  - gemm_nt: 128x128 tile, BK=32, 4 waves, 4x4 mfma_f32_16x16x32_bf16,
//    staging via __builtin_amdgcn_global_load_lds width=16 (no VGPR roundtrip)
//  - qc/kc buffers overlaid by Pb (dead after projections; stream-ordered)

typedef short bf16x8 __attribute__((ext_vector_type(8)));
typedef float f32x4  __attribute__((ext_vector_type(4)));

__device__ __forceinline__ unsigned short f2bf(float f) {
    union { float f; unsigned int i; } x; x.f = f;
    unsigned int r = (x.i + 0x7fffu + ((x.i >> 16) & 1u)) >> 16;  // RNE
    return (unsigned short)r;
}
__device__ __forceinline__ bf16x8 cvt8(const float* p) {
    float4 x0 = *(const float4*)p;
    float4 x1 = *(const float4*)(p + 4);
    bf16x8 r;
    r[0] = (short)f2bf(x0.x); r[1] = (short)f2bf(x0.y);
    r[2] = (short)f2bf(x0.z); r[3] = (short)f2bf(x0.w);
    r[4] = (short)f2bf(x1.x); r[5] = (short)f2bf(x1.y);
    r[6] = (short)f2bf(x1.z); r[7] = (short)f2bf(x1.w);
    return r;
}

// async global->LDS, 16B per lane. LDS dst is wave-uniform base; HW writes
// lane i at base + i*16 (guide §5 / m97). Global src is per-lane.
__device__ __forceinline__ void gl2lds16(const void* g, void* l) {
    __builtin_amdgcn_global_load_lds(
        reinterpret_cast<const __attribute__((address_space(1))) void*>(
            reinterpret_cast<uintptr_t>(g)),
        reinterpret_cast<__attribute__((address_space(3))) void*>(
            (unsigned)reinterpret_cast<uintptr_t>(l)),
        16, 0, 0);
}

// f32 -> bf16 elementwise cast, 8 elems/thread, grid-stride
__global__ __launch_bounds__(256)
void cast_bf16(const float* __restrict__ in, unsigned short* __restrict__ out,
               long n8)
{
    long i = (long)blockIdx.x * blockDim.x + threadIdx.x;
    const long stride = (long)gridDim.x * blockDim.x;
    for (; i < n8; i += stride)
        *(bf16x8*)(out + i * 8) = cvt8(in + i * 8);
}

// Pure-bf16 NT GEMM: C[M,N] = A[M,K] * B[N,K]^T. 128x128 tile, BK=32,
// 256 thr = 4 waves (2x2), each wave 64x64 via 4x4 mfma_f32_16x16x32_bf16.
// Staging: global_load_lds dwordx4, LDS layout = linear in thread order
// (thread t owns bytes [t*16, t*16+16) of each half-tile).
// MODE 0: Qp/Kp = Xb*Wb^T + b   out bf16, bias[col]
// MODE 1: Vt = Wvb*Kp^T + bv    out bf16 [b2][row][lk], bias[row]
// MODE 2: S = Qp*Kp^T *s, mask  out f32, batched via z
// MODE 3: O = Pb*Vt^T           out f32, batched via z
template<int MODE>
__global__ __launch_bounds__(256)
void gemm_nt(const unsigned short* __restrict__ A,
             const unsigned short* __restrict__ B,
             const float* __restrict__ bias,
             const int* __restrict__ mask,
             void* __restrict__ out)
{
    constexpr int K   = (MODE == 3) ? LKN : DDIM;
    constexpr int LDA = K;
    constexpr int LDB = K;

    __shared__ unsigned short lA[128 * 32];
    __shared__ unsigned short lB[128 * 32];

    const int t    = threadIdx.x;
    const int lane = t & 63;
    const int wave = t >> 6;
    const int wm   = wave >> 1;
    const int wn   = wave & 1;

    const int bm = blockIdx.y;
    const int bn = blockIdx.x;
    const int z  = blockIdx.z;

    const unsigned short* Ap = A;
    const unsigned short* Bp = B;
    if (MODE == 2) { Ap += (long)z * LQN * DDIM; Bp += (long)z * LKN * DDIM; }
    if (MODE == 3) { Ap += (long)z * LQN * LKN;  Bp += (long)z * DDIM * LKN; }

    // staging: thread t covers rows (t>>2) and (t>>2)+64, k-chunk (t&3)*8
    const int srow = t >> 2;
    const int skk  = (t & 3) * 8;
    const unsigned short* ga0 = Ap + (long)(bm * 128 + srow) * LDA + skk;
    const unsigned short* ga1 = ga0 + 64L * LDA;
    const unsigned short* gb0 = Bp + (long)(bn * 128 + srow) * LDB + skk;
    const unsigned short* gb1 = gb0 + 64L * LDB;
    // wave-uniform LDS bases: wave w stages bytes [w*1024, w*1024+1024)
    unsigned short* lAw = lA + wave * 512;
    unsigned short* lBw = lB + wave * 512;

    f32x4 acc[4][4];
    #pragma unroll
    for (int i = 0; i < 4; ++i)
        #pragma unroll
        for (int j = 0; j < 4; ++j)
            acc[i][j] = (f32x4)(0.0f);

    const int quad = lane >> 4;
    const int l15  = lane & 15;

    for (int k0 = 0; k0 < K; k0 += 32) {
        __syncthreads();                 // all waves done reading prev LDS
        gl2lds16(ga0 + k0, lAw);         // rows 0..63 of A tile
        gl2lds16(ga1 + k0, lAw + 2048);  // rows 64..127
        gl2lds16(gb0 + k0, lBw);
        gl2lds16(gb1 + k0, lBw + 2048);
        __syncthreads();                 // drains vmcnt(0): LDS data ready

        bf16x8 af[4], bfv[4];
        #pragma unroll
        for (int i = 0; i < 4; ++i)
            af[i] = *(const bf16x8*)&lA[(wm * 64 + i * 16 + l15) * 32 + quad * 8];
        #pragma unroll
        for (int j = 0; j < 4; ++j)
            bfv[j] = *(const bf16x8*)&lB[(wn * 64 + j * 16 + l15) * 32 + quad * 8];

        #pragma unroll
        for (int i = 0; i < 4; ++i)
            #pragma unroll
            for (int j = 0; j < 4; ++j)
                acc[i][j] = __builtin_amdgcn_mfma_f32_16x16x32_bf16(
                    af[i], bfv[j], acc[i][j], 0, 0, 0);
    }

    // epilogue: C/D layout col=lane&15, row=quad*4+r  [measured m89/m91]
    #pragma unroll
    for (int i = 0; i < 4; ++i) {
        #pragma unroll
        for (int j = 0; j < 4; ++j) {
            const int grow = bm * 128 + wm * 64 + i * 16 + quad * 4;
            const int gcol = bn * 128 + wn * 64 + j * 16 + l15;
            if (MODE == 0) {
                const float bc = bias[gcol];
                #pragma unroll
                for (int r = 0; r < 4; ++r)
                    ((unsigned short*)out)[(long)(grow + r) * DDIM + gcol] =
                        f2bf(acc[i][j][r] + bc);
            } else if (MODE == 1) {
                const int b2 = gcol >> 11;        // in-group batch
                const int lk = gcol & 2047;
                #pragma unroll
                for (int r = 0; r < 4; ++r) {
                    const float bc = bias[grow + r];
                    ((unsigned short*)out)[(long)b2 * DDIM * LKN +
                                           (long)(grow + r) * LKN + lk] =
                        f2bf(acc[i][j][r] + bc);
                }
            } else if (MODE == 2) {
                const int mv = mask[z * LKN + gcol];
                #pragma unroll
                for (int r = 0; r < 4; ++r) {
                    float v = acc[i][j][r] * 0.03125f;   // 1/sqrt(1024)
                    if (mv == 0) v = -1e9f;
                    ((float*)out)[(long)z * LQN * LKN +
                                  (long)(grow + r) * LKN + gcol] = v;
                }
            } else {
                #pragma unroll
                for (int r = 0; r < 4; ++r)
                    ((float*)out)[(long)z * LQN * DDIM +
                                  (long)(grow + r) * DDIM + gcol] = acc[i][j][r];
            }
        }
    }
}

// in-place f32 row softmax over LKN scores; one block (256 thr) per row.
// Also emits bf16 copy (Pb) for the O-GEMM (same values the old kernel got
// from cvt8-staging P, so numerics are identical).
__global__ __launch_bounds__(256)
void softmax_rows(float* __restrict__ P, unsigned short* __restrict__ Pb)
{
    const int t = threadIdx.x;
    const long base = (long)blockIdx.x * LKN + t * 8;

    float4 r0 = *(const float4*)&P[base];
    float4 r1 = *(const float4*)&P[base + 4];
    float v[8] = { r0.x, r0.y, r0.z, r0.w, r1.x, r1.y, r1.z, r1.w };

    float m = -3.0e38f;
    #pragma unroll
    for (int i = 0; i < 8; ++i) m = fmaxf(m, v[i]);
    #pragma unroll
    for (int off = 32; off >= 1; off >>= 1) m = fmaxf(m, __shfl_xor(m, off, 64));
    __shared__ float redm[4];
    if ((t & 63) == 0) redm[t >> 6] = m;
    __syncthreads();
    m = fmaxf(fmaxf(redm[0], redm[1]), fmaxf(redm[2], redm[3]));

    float s = 0.0f;
    #pragma unroll
    for (int i = 0; i < 8; ++i) { v[i] = __expf(v[i] - m); s += v[i]; }
    #pragma unroll
    for (int off = 32; off >= 1; off >>= 1) s += __shfl_xor(s, off, 64);
    __shared__ float reds[4];
    if ((t & 63) == 0) reds[t >> 6] = s;
    __syncthreads();
    s = reds[0] + reds[1] + reds[2] + reds[3];

    const float inv = 1.0f / s;   // s >= 1 always (max element contributes 1)
    r0.x = v[0] * inv; r0.y = v[1] * inv; r0.z = v[2] * inv; r0.w = v[3] * inv;
    r1.x = v[4] * inv; r1.y = v[5] * inv; r1.z = v[6] * inv; r1.w = v[7] * inv;
    *(float4*)&P[base]     = r0;
    *(float4*)&P[base + 4] = r1;

    bf16x8 pb;
    pb[0] = (short)f2bf(r0.x); pb[1] = (short)f2bf(r0.y);
    pb[2] = (short)f2bf(r0.z); pb[3] = (short)f2bf(r0.w);
    pb[4] = (short)f2bf(r1.x); pb[5] = (short)f2bf(r1.y);
    pb[6] = (short)f2bf(r1.z); pb[7] = (short)f2bf(r1.w);
    *(bf16x8*)&Pb[base] = pb;
}

extern "C" void kernel_launch(void* const* d_in, const int* in_sizes, int n_in,
                              void* d_out, int out_size, void* d_ws, size_t ws_size,
                              hipStream_t stream)
{
    (void)in_sizes; (void)n_in; (void)out_size;

    const float* key   = (const float*)d_in[0];
    const float* query = (const float*)d_in[1];
    const int*   mask  = (const int*)d_in[2];
    const float* Wq    = (const float*)d_in[3];
    const float* bq    = (const float*)d_in[4];
    const float* Wk    = (const float*)d_in[5];
    const float* bk    = (const float*)d_in[6];
    const float* Wv    = (const float*)d_in[7];
    const float* bv    = (const float*)d_in[8];

    float* outO = (float*)d_out;                          // [B,LQ,D]  f32
    float* outP = outO + (size_t)BBAT * LQN * DDIM;       // [B,LQ,LK] f32

    // fixed workspace: bf16 weights, 3 x 2 MiB
    unsigned short* Wqb  = (unsigned short*)d_ws;
    unsigned short* Wkb  = Wqb + (size_t)DDIM * DDIM;
    unsigned short* Wvb  = Wkb + (size_t)DDIM * DDIM;
    unsigned short* gbuf = Wvb + (size_t)DDIM * DDIM;

    // per-batch: regionA (qc+kc, later overlaid by Pb) = LQN*LKN shorts (8 MiB)
    //            + Qp + Kp + Vt = 3 * LQN*DDIM shorts (12 MiB)  => 20 MiB
    const size_t fixed = (size_t)3 * DDIM * DDIM * sizeof(unsigned short);
    const size_t perB  = ((size_t)LQN * LKN + (size_t)3 * LQN * DDIM) *
                         sizeof(unsigned short);
    size_t avail = (ws_size > fixed) ? (ws_size - fixed) : 0;
    int g = (int)(avail / perB);
    if (g > BBAT) g = BBAT;
    if (g < 1)    g = 1;

    dim3 blk(256, 1, 1);

    // weights -> bf16 (once)
    cast_bf16<<<dim3(512, 1, 1), blk, 0, stream>>>(Wq, Wqb, (long)DDIM * DDIM / 8);
    cast_bf16<<<dim3(512, 1, 1), blk, 0, stream>>>(Wk, Wkb, (long)DDIM * DDIM / 8);
    cast_bf16<<<dim3(512, 1, 1), blk, 0, stream>>>(Wv, Wvb, (long)DDIM * DDIM / 8);

    for (int b0 = 0; b0 < BBAT; b0 += g) {
        const int gl = (BBAT - b0 < g) ? (BBAT - b0) : g;

        unsigned short* regionA = gbuf;                          // gl * 4Mi shorts
        unsigned short* qc = regionA;                            // [gl*LQ, D] bf16
        unsigned short* kc = regionA + (size_t)gl * LQN * DDIM;  // [gl*LK, D] bf16
        unsigned short* Pb = regionA;                            // [gl,LQ,LK] bf16 (overlays qc/kc)
        unsigned short* Qp = regionA + (size_t)gl * LQN * LKN;   // [gl*LQ, D] bf16
        unsigned short* Kp = Qp + (size_t)gl * LQN * DDIM;       // [gl*LK, D] bf16
        unsigned short* Vt = Kp + (size_t)gl * LKN * DDIM;       // [gl, D, LK] bf16

        // inputs -> bf16
        cast_bf16<<<dim3(2048, 1, 1), blk, 0, stream>>>(
            query + (size_t)b0 * LQN * DDIM, qc, (long)gl * LQN * DDIM / 8);
        cast_bf16<<<dim3(2048, 1, 1), blk, 0, stream>>>(
            key + (size_t)b0 * LKN * DDIM, kc, (long)gl * LKN * DDIM / 8);

        // Qp = qc*Wq^T + bq   (M=gl*2048, N=1024, K=1024)
        gemm_nt<0><<<dim3(8, gl * 16, 1), blk, 0, stream>>>(qc, Wqb, bq, nullptr, Qp);

        // Kp = kc*Wk^T + bk
        gemm_nt<0><<<dim3(8, gl * 16, 1), blk, 0, stream>>>(kc, Wkb, bk, nullptr, Kp);

        // Vt[z][d][lk] = Wv*Kp^T + bv   (M=1024, N=gl*2048, K=1024)
        gemm_nt<1><<<dim3(gl * 16, 8, 1), blk, 0, stream>>>(Wvb, Kp, bv, nullptr, Vt);

        // S[z] = Qp[z]*Kp[z]^T * scale, mask fill  (per z: 2048x2048, K=1024)
        gemm_nt<2><<<dim3(16, 16, gl), blk, 0, stream>>>(
            Qp, Kp, nullptr, mask + (size_t)b0 * LKN,
            outP + (size_t)b0 * LQN * LKN);

        // softmax rows in place (f32) + bf16 copy for the O-GEMM
        softmax_rows<<<dim3(gl * LQN, 1, 1), blk, 0, stream>>>(
            outP + (size_t)b0 * LQN * LKN, Pb);

        // O[z] = Pb[z]*Vt[z]^T   (per z: M=2048, N=1024, K=2048)
        gemm_nt<3><<<dim3(8, 16, gl), blk, 0, stream>>>(
            Pb, Vt, nullptr, nullptr, outO + (size_t)b0 * LQN * DDIM);
    }
}

// Round 2
// 720.966 us; speedup vs baseline: 1.1856x; 1.0440x over previous
//
#include <hip/hip_runtime.h>
#include <cstdint>

// Problem constants (B, LQ, LK, D fixed by the reference)
#define DDIM 1024
#define LQN  2048
#define LKN  2048
#define BBAT 8

// ROUND-5: T3-minimum 2-phase double-buffered K-loop + T1 XCD swizzle.
//  - prefetch tile t+1 via global_load_lds into buf^1 BEFORE compute of buf
//  - ONE __syncthreads per K-step (its vmcnt(0)+lgkmcnt(0) drain is the wait)
//  - bijective XCD swizzle of (x,y) plane for L2 panel reuse (nwg%8==0 all modes)
//  - all-bf16 operands (round-4), softmax emits bf16 P copy for O-GEMM

typedef short bf16x8 __attribute__((ext_vector_type(8)));
typedef float f32x4  __attribute__((ext_vector_type(4)));

__device__ __forceinline__ unsigned short f2bf(float f) {
    union { float f; unsigned int i; } x; x.f = f;
    unsigned int r = (x.i + 0x7fffu + ((x.i >> 16) & 1u)) >> 16;  // RNE
    return (unsigned short)r;
}
__device__ __forceinline__ bf16x8 cvt8(const float* p) {
    float4 x0 = *(const float4*)p;
    float4 x1 = *(const float4*)(p + 4);
    bf16x8 r;
    r[0] = (short)f2bf(x0.x); r[1] = (short)f2bf(x0.y);
    r[2] = (short)f2bf(x0.z); r[3] = (short)f2bf(x0.w);
    r[4] = (short)f2bf(x1.x); r[5] = (short)f2bf(x1.y);
    r[6] = (short)f2bf(x1.z); r[7] = (short)f2bf(x1.w);
    return r;
}

// async global->LDS, 16B per lane. LDS dst is wave-uniform base; HW writes
// lane i at base + i*16 (guide §5 / m97). Global src is per-lane.
__device__ __forceinline__ void gl2lds16(const void* g, void* l) {
    __builtin_amdgcn_global_load_lds(
        reinterpret_cast<const __attribute__((address_space(1))) void*>(
            reinterpret_cast<uintptr_t>(g)),
        reinterpret_cast<__attribute__((address_space(3))) void*>(
            (unsigned)reinterpret_cast<uintptr_t>(l)),
        16, 0, 0);
}

// f32 -> bf16 elementwise cast, 8 elems/thread, grid-stride
__global__ __launch_bounds__(256)
void cast_bf16(const float* __restrict__ in, unsigned short* __restrict__ out,
               long n8)
{
    long i = (long)blockIdx.x * blockDim.x + threadIdx.x;
    const long stride = (long)gridDim.x * blockDim.x;
    for (; i < n8; i += stride)
        *(bf16x8*)(out + i * 8) = cvt8(in + i * 8);
}

// Pure-bf16 NT GEMM: C[M,N] = A[M,K] * B[N,K]^T. 128x128 tile, BK=32,
// 256 thr = 4 waves (2x2), each wave 64x64 via 4x4 mfma_f32_16x16x32_bf16.
// 2-phase double-buffered LDS: stage(t+1) || compute(t), 1 barrier/K-step.
// MODE 0: Qp/Kp = Xb*Wb^T + b   out bf16, bias[col]
// MODE 1: Vt = Wvb*Kp^T + bv    out bf16 [b2][row][lk], bias[row]
// MODE 2: S = Qp*Kp^T *s, mask  out f32, batched via z
// MODE 3: O = Pb*Vt^T           out f32, batched via z
template<int MODE>
__global__ __launch_bounds__(256)
void gemm_nt(const unsigned short* __restrict__ A,
             const unsigned short* __restrict__ B,
             const float* __restrict__ bias,
             const int* __restrict__ mask,
             void* __restrict__ out)
{
    constexpr int K   = (MODE == 3) ? LKN : DDIM;
    constexpr int LDA = K;
    constexpr int LDB = K;
    constexpr int NT  = K / 32;

    // [buf][ A: shorts 0..4095 | B: shorts 4096..8191 ]  (32 KiB total)
    __shared__ unsigned short lds[2][8192];

    const int t    = threadIdx.x;
    const int lane = t & 63;
    const int wave = t >> 6;
    const int wm   = wave >> 1;
    const int wn   = wave & 1;

    // T1: bijective XCD swizzle of the (x,y) plane (nwg % 8 == 0 in all modes)
    const int gx   = gridDim.x;
    const int nwg  = gx * gridDim.y;
    const int bid0 = blockIdx.y * gx + blockIdx.x;
    const int bid  = ((nwg & 7) == 0) ? ((bid0 & 7) * (nwg >> 3) + (bid0 >> 3))
                                      : bid0;
    const int bm = bid / gx;
    const int bn = bid % gx;
    const int z  = blockIdx.z;

    const unsigned short* Ap = A;
    const unsigned short* Bp = B;
    if (MODE == 2) { Ap += (long)z * LQN * DDIM; Bp += (long)z * LKN * DDIM; }
    if (MODE == 3) { Ap += (long)z * LQN * LKN;  Bp += (long)z * DDIM * LKN; }

    // staging: thread t covers rows (t>>2) and (t>>2)+64, k-chunk (t&3)*8
    const int srow = t >> 2;
    const int skk  = (t & 3) * 8;
    const unsigned short* ga0 = Ap + (long)(bm * 128 + srow) * LDA + skk;
    const unsigned short* ga1 = ga0 + 64L * LDA;
    const unsigned short* gb0 = Bp + (long)(bn * 128 + srow) * LDB + skk;
    const unsigned short* gb1 = gb0 + 64L * LDB;
    const int woff = wave * 512;   // wave-uniform LDS base (shorts)

    f32x4 acc[4][4];
    #pragma unroll
    for (int i = 0; i < 4; ++i)
        #pragma unroll
        for (int j = 0; j < 4; ++j)
            acc[i][j] = (f32x4)(0.0f);

    const int quad = lane >> 4;
    const int l15  = lane & 15;

    // stage K-tile kk into buffer bufp
#define STAGE(bufp, kk) do {                              \
        gl2lds16(ga0 + (kk), (bufp) + woff);              \
        gl2lds16(ga1 + (kk), (bufp) + woff + 2048);       \
        gl2lds16(gb0 + (kk), (bufp) + 4096 + woff);       \
        gl2lds16(gb1 + (kk), (bufp) + 4096 + woff + 2048);\
    } while (0)

    unsigned short* cur = &lds[0][0];
    unsigned short* nxt = &lds[1][0];

    STAGE(cur, 0);
    __syncthreads();                       // drain prologue loads

    for (int tt = 0; tt < NT; ++tt) {
        if (tt + 1 < NT)
            STAGE(nxt, (tt + 1) * 32);     // prefetch next tile (in flight)

        bf16x8 af[4], bfv[4];
        #pragma unroll
        for (int i = 0; i < 4; ++i)
            af[i] = *(const bf16x8*)&cur[(wm * 64 + i * 16 + l15) * 32 + quad * 8];
        #pragma unroll
        for (int j = 0; j < 4; ++j)
            bfv[j] = *(const bf16x8*)&cur[4096 + (wn * 64 + j * 16 + l15) * 32 + quad * 8];

        #pragma unroll
        for (int i = 0; i < 4; ++i)
            #pragma unroll
            for (int j = 0; j < 4; ++j)
                acc[i][j] = __builtin_amdgcn_mfma_f32_16x16x32_bf16(
                    af[i], bfv[j], acc[i][j], 0, 0, 0);

        __syncthreads();                   // vmcnt(0)+lgkmcnt(0) drain + barrier
        unsigned short* tmp = cur; cur = nxt; nxt = tmp;
    }
#undef STAGE

    // epilogue: C/D layout col=lane&15, row=quad*4+r  [measured m89/m91]
    #pragma unroll
    for (int i = 0; i < 4; ++i) {
        #pragma unroll
        for (int j = 0; j < 4; ++j) {
            const int grow = bm * 128 + wm * 64 + i * 16 + quad * 4;
            const int gcol = bn * 128 + wn * 64 + j * 16 + l15;
            if (MODE == 0) {
                const float bc = bias[gcol];
                #pragma unroll
                for (int r = 0; r < 4; ++r)
                    ((unsigned short*)out)[(long)(grow + r) * DDIM + gcol] =
                        f2bf(acc[i][j][r] + bc);
            } else if (MODE == 1) {
                const int b2 = gcol >> 11;        // in-group batch
                const int lk = gcol & 2047;
                #pragma unroll
                for (int r = 0; r < 4; ++r) {
                    const float bc = bias[grow + r];
                    ((unsigned short*)out)[(long)b2 * DDIM * LKN +
                                           (long)(grow + r) * LKN + lk] =
                        f2bf(acc[i][j][r] + bc);
                }
            } else if (MODE == 2) {
                const int mv = mask[z * LKN + gcol];
                #pragma unroll
                for (int r = 0; r < 4; ++r) {
                    float v = acc[i][j][r] * 0.03125f;   // 1/sqrt(1024)
                    if (mv == 0) v = -1e9f;
                    ((float*)out)[(long)z * LQN * LKN +
                                  (long)(grow + r) * LKN + gcol] = v;
                }
            } else {
                #pragma unroll
                for (int r = 0; r < 4; ++r)
                    ((float*)out)[(long)z * LQN * DDIM +
                                  (long)(grow + r) * DDIM + gcol] = acc[i][j][r];
            }
        }
    }
}

// in-place f32 row softmax over LKN scores; one block (256 thr) per row.
// Also emits bf16 copy (Pb) for the O-GEMM.
__global__ __launch_bounds__(256)
void softmax_rows(float* __restrict__ P, unsigned short* __restrict__ Pb)
{
    const int t = threadIdx.x;
    const long base = (long)blockIdx.x * LKN + t * 8;

    float4 r0 = *(const float4*)&P[base];
    float4 r1 = *(const float4*)&P[base + 4];
    float v[8] = { r0.x, r0.y, r0.z, r0.w, r1.x, r1.y, r1.z, r1.w };

    float m = -3.0e38f;
    #pragma unroll
    for (int i = 0; i < 8; ++i) m = fmaxf(m, v[i]);
    #pragma unroll
    for (int off = 32; off >= 1; off >>= 1) m = fmaxf(m, __shfl_xor(m, off, 64));
    __shared__ float redm[4];
    if ((t & 63) == 0) redm[t >> 6] = m;
    __syncthreads();
    m = fmaxf(fmaxf(redm[0], redm[1]), fmaxf(redm[2], redm[3]));

    float s = 0.0f;
    #pragma unroll
    for (int i = 0; i < 8; ++i) { v[i] = __expf(v[i] - m); s += v[i]; }
    #pragma unroll
    for (int off = 32; off >= 1; off >>= 1) s += __shfl_xor(s, off, 64);
    __shared__ float reds[4];
    if ((t & 63) == 0) reds[t >> 6] = s;
    __syncthreads();
    s = reds[0] + reds[1] + reds[2] + reds[3];

    const float inv = 1.0f / s;   // s >= 1 always (max element contributes 1)
    r0.x = v[0] * inv; r0.y = v[1] * inv; r0.z = v[2] * inv; r0.w = v[3] * inv;
    r1.x = v[4] * inv; r1.y = v[5] * inv; r1.z = v[6] * inv; r1.w = v[7] * inv;
    *(float4*)&P[base]     = r0;
    *(float4*)&P[base + 4] = r1;

    bf16x8 pb;
    pb[0] = (short)f2bf(r0.x); pb[1] = (short)f2bf(r0.y);
    pb[2] = (short)f2bf(r0.z); pb[3] = (short)f2bf(r0.w);
    pb[4] = (short)f2bf(r1.x); pb[5] = (short)f2bf(r1.y);
    pb[6] = (short)f2bf(r1.z); pb[7] = (short)f2bf(r1.w);
    *(bf16x8*)&Pb[base] = pb;
}

extern "C" void kernel_launch(void* const* d_in, const int* in_sizes, int n_in,
                              void* d_out, int out_size, void* d_ws, size_t ws_size,
                              hipStream_t stream)
{
    (void)in_sizes; (void)n_in; (void)out_size;

    const float* key   = (const float*)d_in[0];
    const float* query = (const float*)d_in[1];
    const int*   mask  = (const int*)d_in[2];
    const float* Wq    = (const float*)d_in[3];
    const float* bq    = (const float*)d_in[4];
    const float* Wk    = (const float*)d_in[5];
    const float* bk    = (const float*)d_in[6];
    const float* Wv    = (const float*)d_in[7];
    const float* bv    = (const float*)d_in[8];

    float* outO = (float*)d_out;                          // [B,LQ,D]  f32
    float* outP = outO + (size_t)BBAT * LQN * DDIM;       // [B,LQ,LK] f32

    // fixed workspace: bf16 weights, 3 x 2 MiB
    unsigned short* Wqb  = (unsigned short*)d_ws;
    unsigned short* Wkb  = Wqb + (size_t)DDIM * DDIM;
    unsigned short* Wvb  = Wkb + (size_t)DDIM * DDIM;
    unsigned short* gbuf = Wvb + (size_t)DDIM * DDIM;

    // per-batch: regionA (qc+kc, later overlaid by Pb) = LQN*LKN shorts (8 MiB)
    //            + Qp + Kp + Vt = 3 * LQN*DDIM shorts (12 MiB)  => 20 MiB
    const size_t fixed = (size_t)3 * DDIM * DDIM * sizeof(unsigned short);
    const size_t perB  = ((size_t)LQN * LKN + (size_t)3 * LQN * DDIM) *
                         sizeof(unsigned short);
    size_t avail = (ws_size > fixed) ? (ws_size - fixed) : 0;
    int g = (int)(avail / perB);
    if (g > BBAT) g = BBAT;
    if (g < 1)    g = 1;

    dim3 blk(256, 1, 1);

    // weights -> bf16 (once)
    cast_bf16<<<dim3(512, 1, 1), blk, 0, stream>>>(Wq, Wqb, (long)DDIM * DDIM / 8);
    cast_bf16<<<dim3(512, 1, 1), blk, 0, stream>>>(Wk, Wkb, (long)DDIM * DDIM / 8);
    cast_bf16<<<dim3(512, 1, 1), blk, 0, stream>>>(Wv, Wvb, (long)DDIM * DDIM / 8);

    for (int b0 = 0; b0 < BBAT; b0 += g) {
        const int gl = (BBAT - b0 < g) ? (BBAT - b0) : g;

        unsigned short* regionA = gbuf;                          // gl * 4Mi shorts
        unsigned short* qc = regionA;                            // [gl*LQ, D] bf16
        unsigned short* kc = regionA + (size_t)gl * LQN * DDIM;  // [gl*LK, D] bf16
        unsigned short* Pb = regionA;                            // [gl,LQ,LK] bf16 (overlays qc/kc)
        unsigned short* Qp = regionA + (size_t)gl * LQN * LKN;   // [gl*LQ, D] bf16
        unsigned short* Kp = Qp + (size_t)gl * LQN * DDIM;       // [gl*LK, D] bf16
        unsigned short* Vt = Kp + (size_t)gl * LKN * DDIM;       // [gl, D, LK] bf16

        // inputs -> bf16
        cast_bf16<<<dim3(2048, 1, 1), blk, 0, stream>>>(
            query + (size_t)b0 * LQN * DDIM, qc, (long)gl * LQN * DDIM / 8);
        cast_bf16<<<dim3(2048, 1, 1), blk, 0, stream>>>(
            key + (size_t)b0 * LKN * DDIM, kc, (long)gl * LKN * DDIM / 8);

        // Qp = qc*Wq^T + bq   (M=gl*2048, N=1024, K=1024)
        gemm_nt<0><<<dim3(8, gl * 16, 1), blk, 0, stream>>>(qc, Wqb, bq, nullptr, Qp);

        // Kp = kc*Wk^T + bk
        gemm_nt<0><<<dim3(8, gl * 16, 1), blk, 0, stream>>>(kc, Wkb, bk, nullptr, Kp);

        // Vt[z][d][lk] = Wv*Kp^T + bv   (M=1024, N=gl*2048, K=1024)
        gemm_nt<1><<<dim3(gl * 16, 8, 1), blk, 0, stream>>>(Wvb, Kp, bv, nullptr, Vt);

        // S[z] = Qp[z]*Kp[z]^T * scale, mask fill  (per z: 2048x2048, K=1024)
        gemm_nt<2><<<dim3(16, 16, gl), blk, 0, stream>>>(
            Qp, Kp, nullptr, mask + (size_t)b0 * LKN,
            outP + (size_t)b0 * LQN * LKN);

        // softmax rows in place (f32) + bf16 copy for the O-GEMM
        softmax_rows<<<dim3(gl * LQN, 1, 1), blk, 0, stream>>>(
            outP + (size_t)b0 * LQN * LKN, Pb);

        // O[z] = Pb[z]*Vt[z]^T   (per z: M=2048, N=1024, K=2048)
        gemm_nt<3><<<dim3(8, 16, gl), blk, 0, stream>>>(
            Pb, Vt, nullptr, nullptr, outO + (size_t)b0 * LQN * DDIM);
    }
}

// Round 3
// 623.147 us; speedup vs baseline: 1.3718x; 1.1570x over previous
//
#include <hip/hip_runtime.h>
#include <cstdint>

// Problem constants (B, LQ, LK, D fixed by the reference)
#define DDIM 1024
#define LQN  2048
#define LKN  2048
#define BBAT 8

// ROUND-6: counted-vmcnt deep pipeline (T3+T4) at 256x256, BK=32.
//  - 3 LDS buffers (96 KiB): compute t | t+1 confirmed | t+2 in flight
//  - end of iter: s_waitcnt vmcnt(4) (tile t+1's 4 loads) + RAW s_barrier
//    -> loads stay in flight across barriers, never drain to 0 mid-loop
//  - 8 waves (512 thr), per-wave 128x64 output, acc[8][4], 32 MFMA/K-tile
//  - T5 setprio(1) around MFMA cluster
//  - grids: 256 blocks (mode0/1/3), 512 (mode2) = 1 block/CU exact fit
//  - all-bf16 operands; softmax emits bf16 P for O-GEMM (rounds 4-5)

typedef short bf16x8 __attribute__((ext_vector_type(8)));
typedef float f32x4  __attribute__((ext_vector_type(4)));

__device__ __forceinline__ unsigned short f2bf(float f) {
    union { float f; unsigned int i; } x; x.f = f;
    unsigned int r = (x.i + 0x7fffu + ((x.i >> 16) & 1u)) >> 16;  // RNE
    return (unsigned short)r;
}
__device__ __forceinline__ bf16x8 cvt8(const float* p) {
    float4 x0 = *(const float4*)p;
    float4 x1 = *(const float4*)(p + 4);
    bf16x8 r;
    r[0] = (short)f2bf(x0.x); r[1] = (short)f2bf(x0.y);
    r[2] = (short)f2bf(x0.z); r[3] = (short)f2bf(x0.w);
    r[4] = (short)f2bf(x1.x); r[5] = (short)f2bf(x1.y);
    r[6] = (short)f2bf(x1.z); r[7] = (short)f2bf(x1.w);
    return r;
}

// async global->LDS, 16B per lane. LDS dst is wave-uniform base; HW writes
// lane i at base + i*16. Global src is per-lane. One vmcnt event per wave.
__device__ __forceinline__ void gl2lds16(const void* g, void* l) {
    __builtin_amdgcn_global_load_lds(
        reinterpret_cast<const __attribute__((address_space(1))) void*>(
            reinterpret_cast<uintptr_t>(g)),
        reinterpret_cast<__attribute__((address_space(3))) void*>(
            (unsigned)reinterpret_cast<uintptr_t>(l)),
        16, 0, 0);
}

// f32 -> bf16 elementwise cast, 8 elems/thread, grid-stride
__global__ __launch_bounds__(256)
void cast_bf16(const float* __restrict__ in, unsigned short* __restrict__ out,
               long n8)
{
    long i = (long)blockIdx.x * blockDim.x + threadIdx.x;
    const long stride = (long)gridDim.x * blockDim.x;
    for (; i < n8; i += stride)
        *(bf16x8*)(out + i * 8) = cvt8(in + i * 8);
}

// Pure-bf16 NT GEMM: C[M,N] = A[M,K] * B[N,K]^T. 256x256 tile, BK=32,
// 512 thr = 8 waves (2M x 4N), wave tile 128x64 via 8x4 mfma_f32_16x16x32_bf16.
// MODE 0: Qp/Kp = Xb*Wb^T + b   out bf16, bias[col]
// MODE 1: Vt = Wvb*Kp^T + bv    out bf16 [b2][row][lk], bias[row]
// MODE 2: S = Qp*Kp^T *s, mask  out f32, batched via z
// MODE 3: O = Pb*Vt^T           out f32, batched via z
template<int MODE>
__global__ __launch_bounds__(512)
void gemm_nt(const unsigned short* __restrict__ A,
             const unsigned short* __restrict__ B,
             const float* __restrict__ bias,
             const int* __restrict__ mask,
             void* __restrict__ out)
{
    constexpr int K   = (MODE == 3) ? LKN : DDIM;
    constexpr int LDA = K;
    constexpr int LDB = K;
    constexpr int NT  = K / 32;          // >= 32 always

    // 3 buffers, each: A[256][32] (8192 shorts) + B[256][32] (8192 shorts)
    __shared__ unsigned short lds[3 * 16384];

    const int t    = threadIdx.x;
    const int lane = t & 63;
    const int wave = t >> 6;             // 0..7
    const int wm   = wave >> 2;          // 0..1  (M half)
    const int wn   = wave & 3;           // 0..3  (N quarter)

    // T1: bijective XCD swizzle of the (x,y) plane (nwg % 8 == 0 all modes)
    const int gx   = gridDim.x;
    const int nwg  = gx * gridDim.y;
    const int bid0 = blockIdx.y * gx + blockIdx.x;
    const int bid  = ((nwg & 7) == 0) ? ((bid0 & 7) * (nwg >> 3) + (bid0 >> 3))
                                      : bid0;
    const int bm = bid / gx;
    const int bn = bid % gx;
    const int z  = blockIdx.z;

    const unsigned short* Ap = A;
    const unsigned short* Bp = B;
    if (MODE == 2) { Ap += (long)z * LQN * DDIM; Bp += (long)z * LKN * DDIM; }
    if (MODE == 3) { Ap += (long)z * LQN * LKN;  Bp += (long)z * DDIM * LKN; }

    // staging: thread t covers rows (t>>2) and (t>>2)+128, k-chunk (t&3)*8
    const int srow = t >> 2;             // 0..127
    const int skk  = (t & 3) * 8;        // 0,8,16,24
    const unsigned short* ga0 = Ap + (long)(bm * 256 + srow) * LDA + skk;
    const unsigned short* ga1 = ga0 + 128L * LDA;
    const unsigned short* gb0 = Bp + (long)(bn * 256 + srow) * LDB + skk;
    const unsigned short* gb1 = gb0 + 128L * LDB;
    const int woff = wave * 512;         // wave-uniform LDS chunk (shorts)

    f32x4 acc[8][4];
    #pragma unroll
    for (int i = 0; i < 8; ++i)
        #pragma unroll
        for (int j = 0; j < 4; ++j)
            acc[i][j] = (f32x4)(0.0f);

    const int quad = lane >> 4;
    const int l15  = lane & 15;

    // stage K-tile kt into buffer bi (4 vmcnt events per wave)
#define STAGE(bi, kt) do {                                              \
        unsigned short* sb = &lds[(bi) * 16384];                        \
        const int ko = (kt) * 32;                                       \
        gl2lds16(ga0 + ko, sb + woff);                                  \
        gl2lds16(ga1 + ko, sb + 4096  + woff);                          \
        gl2lds16(gb0 + ko, sb + 8192  + woff);                          \
        gl2lds16(gb1 + ko, sb + 12288 + woff);                          \
    } while (0)

    // prologue: tiles 0 and 1 in flight; confirm tile 0 (4 oldest of 8)
    STAGE(0, 0);
    STAGE(1, 1);
    asm volatile("s_waitcnt vmcnt(4)" ::: "memory");
    __builtin_amdgcn_s_barrier();

    int cb = 0;
    for (int tt = 0; tt < NT; ++tt) {
        const int nb = (cb + 2 >= 3) ? (cb - 1) : (cb + 2);
        const bool st = (tt + 2 < NT);
        if (st) STAGE(nb, tt + 2);       // buffer nb last read in iter tt-1

        const unsigned short* sb = &lds[cb * 16384];
        bf16x8 af[8], bfv[4];
        #pragma unroll
        for (int j = 0; j < 4; ++j)
            bfv[j] = *(const bf16x8*)&sb[8192 + (wn * 64 + j * 16 + l15) * 32 + quad * 8];
        #pragma unroll
        for (int i = 0; i < 8; ++i)
            af[i] = *(const bf16x8*)&sb[(wm * 128 + i * 16 + l15) * 32 + quad * 8];

        __builtin_amdgcn_s_setprio(1);
        #pragma unroll
        for (int i = 0; i < 8; ++i)
            #pragma unroll
            for (int j = 0; j < 4; ++j)
                acc[i][j] = __builtin_amdgcn_mfma_f32_16x16x32_bf16(
                    af[i], bfv[j], acc[i][j], 0, 0, 0);
        __builtin_amdgcn_s_setprio(0);

        // confirm tile tt+1 (my wave's 4 oldest); tile tt+2 stays in flight
        if (st) asm volatile("s_waitcnt vmcnt(4)" ::: "memory");
        else    asm volatile("s_waitcnt vmcnt(0)" ::: "memory");
        __builtin_amdgcn_s_barrier();
        cb = (cb + 1 >= 3) ? 0 : (cb + 1);
    }
#undef STAGE

    // epilogue: C/D layout col=lane&15, row=quad*4+r  [measured m89/m91]
    #pragma unroll
    for (int i = 0; i < 8; ++i) {
        #pragma unroll
        for (int j = 0; j < 4; ++j) {
            const int grow = bm * 256 + wm * 128 + i * 16 + quad * 4;
            const int gcol = bn * 256 + wn * 64 + j * 16 + l15;
            if (MODE == 0) {
                const float bc = bias[gcol];
                #pragma unroll
                for (int r = 0; r < 4; ++r)
                    ((unsigned short*)out)[(long)(grow + r) * DDIM + gcol] =
                        f2bf(acc[i][j][r] + bc);
            } else if (MODE == 1) {
                const int b2 = gcol >> 11;        // in-group batch
                const int lk = gcol & 2047;
                #pragma unroll
                for (int r = 0; r < 4; ++r) {
                    const float bc = bias[grow + r];
                    ((unsigned short*)out)[(long)b2 * DDIM * LKN +
                                           (long)(grow + r) * LKN + lk] =
                        f2bf(acc[i][j][r] + bc);
                }
            } else if (MODE == 2) {
                const int mv = mask[z * LKN + gcol];
                #pragma unroll
                for (int r = 0; r < 4; ++r) {
                    float v = acc[i][j][r] * 0.03125f;   // 1/sqrt(1024)
                    if (mv == 0) v = -1e9f;
                    ((float*)out)[(long)z * LQN * LKN +
                                  (long)(grow + r) * LKN + gcol] = v;
                }
            } else {
                #pragma unroll
                for (int r = 0; r < 4; ++r)
                    ((float*)out)[(long)z * LQN * DDIM +
                                  (long)(grow + r) * DDIM + gcol] = acc[i][j][r];
            }
        }
    }
}

// in-place f32 row softmax over LKN scores; one block (256 thr) per row.
// Also emits bf16 copy (Pb) for the O-GEMM.
__global__ __launch_bounds__(256)
void softmax_rows(float* __restrict__ P, unsigned short* __restrict__ Pb)
{
    const int t = threadIdx.x;
    const long base = (long)blockIdx.x * LKN + t * 8;

    float4 r0 = *(const float4*)&P[base];
    float4 r1 = *(const float4*)&P[base + 4];
    float v[8] = { r0.x, r0.y, r0.z, r0.w, r1.x, r1.y, r1.z, r1.w };

    float m = -3.0e38f;
    #pragma unroll
    for (int i = 0; i < 8; ++i) m = fmaxf(m, v[i]);
    #pragma unroll
    for (int off = 32; off >= 1; off >>= 1) m = fmaxf(m, __shfl_xor(m, off, 64));
    __shared__ float redm[4];
    if ((t & 63) == 0) redm[t >> 6] = m;
    __syncthreads();
    m = fmaxf(fmaxf(redm[0], redm[1]), fmaxf(redm[2], redm[3]));

    float s = 0.0f;
    #pragma unroll
    for (int i = 0; i < 8; ++i) { v[i] = __expf(v[i] - m); s += v[i]; }
    #pragma unroll
    for (int off = 32; off >= 1; off >>= 1) s += __shfl_xor(s, off, 64);
    __shared__ float reds[4];
    if ((t & 63) == 0) reds[t >> 6] = s;
    __syncthreads();
    s = reds[0] + reds[1] + reds[2] + reds[3];

    const float inv = 1.0f / s;   // s >= 1 always (max element contributes 1)
    r0.x = v[0] * inv; r0.y = v[1] * inv; r0.z = v[2] * inv; r0.w = v[3] * inv;
    r1.x = v[4] * inv; r1.y = v[5] * inv; r1.z = v[6] * inv; r1.w = v[7] * inv;
    *(float4*)&P[base]     = r0;
    *(float4*)&P[base + 4] = r1;

    bf16x8 pb;
    pb[0] = (short)f2bf(r0.x); pb[1] = (short)f2bf(r0.y);
    pb[2] = (short)f2bf(r0.z); pb[3] = (short)f2bf(r0.w);
    pb[4] = (short)f2bf(r1.x); pb[5] = (short)f2bf(r1.y);
    pb[6] = (short)f2bf(r1.z); pb[7] = (short)f2bf(r1.w);
    *(bf16x8*)&Pb[base] = pb;
}

extern "C" void kernel_launch(void* const* d_in, const int* in_sizes, int n_in,
                              void* d_out, int out_size, void* d_ws, size_t ws_size,
                              hipStream_t stream)
{
    (void)in_sizes; (void)n_in; (void)out_size;

    const float* key   = (const float*)d_in[0];
    const float* query = (const float*)d_in[1];
    const int*   mask  = (const int*)d_in[2];
    const float* Wq    = (const float*)d_in[3];
    const float* bq    = (const float*)d_in[4];
    const float* Wk    = (const float*)d_in[5];
    const float* bk    = (const float*)d_in[6];
    const float* Wv    = (const float*)d_in[7];
    const float* bv    = (const float*)d_in[8];

    float* outO = (float*)d_out;                          // [B,LQ,D]  f32
    float* outP = outO + (size_t)BBAT * LQN * DDIM;       // [B,LQ,LK] f32

    // fixed workspace: bf16 weights, 3 x 2 MiB
    unsigned short* Wqb  = (unsigned short*)d_ws;
    unsigned short* Wkb  = Wqb + (size_t)DDIM * DDIM;
    unsigned short* Wvb  = Wkb + (size_t)DDIM * DDIM;
    unsigned short* gbuf = Wvb + (size_t)DDIM * DDIM;

    // per-batch: regionA (qc+kc, later overlaid by Pb) = LQN*LKN shorts (8 MiB)
    //            + Qp + Kp + Vt = 3 * LQN*DDIM shorts (12 MiB)  => 20 MiB
    const size_t fixed = (size_t)3 * DDIM * DDIM * sizeof(unsigned short);
    const size_t perB  = ((size_t)LQN * LKN + (size_t)3 * LQN * DDIM) *
                         sizeof(unsigned short);
    size_t avail = (ws_size > fixed) ? (ws_size - fixed) : 0;
    int g = (int)(avail / perB);
    if (g > BBAT) g = BBAT;
    if (g < 1)    g = 1;

    dim3 blk(256, 1, 1);
    dim3 gblk(512, 1, 1);

    // weights -> bf16 (once)
    cast_bf16<<<dim3(512, 1, 1), blk, 0, stream>>>(Wq, Wqb, (long)DDIM * DDIM / 8);
    cast_bf16<<<dim3(512, 1, 1), blk, 0, stream>>>(Wk, Wkb, (long)DDIM * DDIM / 8);
    cast_bf16<<<dim3(512, 1, 1), blk, 0, stream>>>(Wv, Wvb, (long)DDIM * DDIM / 8);

    for (int b0 = 0; b0 < BBAT; b0 += g) {
        const int gl = (BBAT - b0 < g) ? (BBAT - b0) : g;

        unsigned short* regionA = gbuf;                          // gl * 4Mi shorts
        unsigned short* qc = regionA;                            // [gl*LQ, D] bf16
        unsigned short* kc = regionA + (size_t)gl * LQN * DDIM;  // [gl*LK, D] bf16
        unsigned short* Pb = regionA;                            // [gl,LQ,LK] bf16 (overlays qc/kc)
        unsigned short* Qp = regionA + (size_t)gl * LQN * LKN;   // [gl*LQ, D] bf16
        unsigned short* Kp = Qp + (size_t)gl * LQN * DDIM;       // [gl*LK, D] bf16
        unsigned short* Vt = Kp + (size_t)gl * LKN * DDIM;       // [gl, D, LK] bf16

        // inputs -> bf16
        cast_bf16<<<dim3(2048, 1, 1), blk, 0, stream>>>(
            query + (size_t)b0 * LQN * DDIM, qc, (long)gl * LQN * DDIM / 8);
        cast_bf16<<<dim3(2048, 1, 1), blk, 0, stream>>>(
            key + (size_t)b0 * LKN * DDIM, kc, (long)gl * LKN * DDIM / 8);

        // Qp = qc*Wq^T + bq   (M=gl*2048, N=1024, K=1024)
        gemm_nt<0><<<dim3(4, gl * 8, 1), gblk, 0, stream>>>(qc, Wqb, bq, nullptr, Qp);

        // Kp = kc*Wk^T + bk
        gemm_nt<0><<<dim3(4, gl * 8, 1), gblk, 0, stream>>>(kc, Wkb, bk, nullptr, Kp);

        // Vt[z][d][lk] = Wv*Kp^T + bv   (M=1024, N=gl*2048, K=1024)
        gemm_nt<1><<<dim3(gl * 8, 4, 1), gblk, 0, stream>>>(Wvb, Kp, bv, nullptr, Vt);

        // S[z] = Qp[z]*Kp[z]^T * scale, mask fill  (per z: 2048x2048, K=1024)
        gemm_nt<2><<<dim3(8, 8, gl), gblk, 0, stream>>>(
            Qp, Kp, nullptr, mask + (size_t)b0 * LKN,
            outP + (size_t)b0 * LQN * LKN);

        // softmax rows in place (f32) + bf16 copy for the O-GEMM
        softmax_rows<<<dim3(gl * LQN, 1, 1), blk, 0, stream>>>(
            outP + (size_t)b0 * LQN * LKN, Pb);

        // O[z] = Pb[z]*Vt[z]^T   (per z: M=2048, N=1024, K=2048)
        gemm_nt<3><<<dim3(4, 8, gl), gblk, 0, stream>>>(
            Pb, Vt, nullptr, nullptr, outO + (size_t)b0 * LQN * DDIM);
    }
}

// Round 4
// 612.030 us; speedup vs baseline: 1.3967x; 1.0182x over previous
//
#include <hip/hip_runtime.h>
#include <cstdint>

// Problem constants (B, LQ, LK, D fixed by the reference)
#define DDIM 1024
#define LQN  2048
#define LKN  2048
#define BBAT 8

// ROUND-7: + T2 LDS XOR-swizzle on top of the counted-vmcnt deep pipeline.
//  - k-chunk (16B) index XORed with (row>>1)&3, BOTH sides (rule #21):
//    staging pre-swizzles the per-lane GLOBAL source k-chunk (LDS dest stays
//    linear, as global_load_lds requires); reads apply the same XOR.
//  - removes the ~8-way quarter-wave bank conflict of [row][32] chunk reads
//    (SQ_LDS_BANK_CONFLICT was 8.4M/dispatch through rounds 0-6)
//  - everything else unchanged from round-6 (3-buffer vmcnt(4) pipeline,
//    8 waves, 256x256/BK=32, T1 swizzle, T5 setprio, all-bf16 operands)

typedef short bf16x8 __attribute__((ext_vector_type(8)));
typedef float f32x4  __attribute__((ext_vector_type(4)));

__device__ __forceinline__ unsigned short f2bf(float f) {
    union { float f; unsigned int i; } x; x.f = f;
    unsigned int r = (x.i + 0x7fffu + ((x.i >> 16) & 1u)) >> 16;  // RNE
    return (unsigned short)r;
}
__device__ __forceinline__ bf16x8 cvt8(const float* p) {
    float4 x0 = *(const float4*)p;
    float4 x1 = *(const float4*)(p + 4);
    bf16x8 r;
    r[0] = (short)f2bf(x0.x); r[1] = (short)f2bf(x0.y);
    r[2] = (short)f2bf(x0.z); r[3] = (short)f2bf(x0.w);
    r[4] = (short)f2bf(x1.x); r[5] = (short)f2bf(x1.y);
    r[6] = (short)f2bf(x1.z); r[7] = (short)f2bf(x1.w);
    return r;
}

// async global->LDS, 16B per lane. LDS dst is wave-uniform base; HW writes
// lane i at base + i*16. Global src is per-lane (enables source pre-swizzle).
__device__ __forceinline__ void gl2lds16(const void* g, void* l) {
    __builtin_amdgcn_global_load_lds(
        reinterpret_cast<const __attribute__((address_space(1))) void*>(
            reinterpret_cast<uintptr_t>(g)),
        reinterpret_cast<__attribute__((address_space(3))) void*>(
            (unsigned)reinterpret_cast<uintptr_t>(l)),
        16, 0, 0);
}

// f32 -> bf16 elementwise cast, 8 elems/thread, grid-stride
__global__ __launch_bounds__(256)
void cast_bf16(const float* __restrict__ in, unsigned short* __restrict__ out,
               long n8)
{
    long i = (long)blockIdx.x * blockDim.x + threadIdx.x;
    const long stride = (long)gridDim.x * blockDim.x;
    for (; i < n8; i += stride)
        *(bf16x8*)(out + i * 8) = cvt8(in + i * 8);
}

// Pure-bf16 NT GEMM: C[M,N] = A[M,K] * B[N,K]^T. 256x256 tile, BK=32,
// 512 thr = 8 waves (2M x 4N), wave tile 128x64 via 8x4 mfma_f32_16x16x32_bf16.
// MODE 0: Qp/Kp = Xb*Wb^T + b   out bf16, bias[col]
// MODE 1: Vt = Wvb*Kp^T + bv    out bf16 [b2][row][lk], bias[row]
// MODE 2: S = Qp*Kp^T *s, mask  out f32, batched via z
// MODE 3: O = Pb*Vt^T           out f32, batched via z
template<int MODE>
__global__ __launch_bounds__(512)
void gemm_nt(const unsigned short* __restrict__ A,
             const unsigned short* __restrict__ B,
             const float* __restrict__ bias,
             const int* __restrict__ mask,
             void* __restrict__ out)
{
    constexpr int K   = (MODE == 3) ? LKN : DDIM;
    constexpr int LDA = K;
    constexpr int LDB = K;
    constexpr int NT  = K / 32;          // >= 32 always

    // 3 buffers, each: A[256][32] (8192 shorts) + B[256][32] (8192 shorts)
    __shared__ unsigned short lds[3 * 16384];

    const int t    = threadIdx.x;
    const int lane = t & 63;
    const int wave = t >> 6;             // 0..7
    const int wm   = wave >> 2;          // 0..1  (M half)
    const int wn   = wave & 3;           // 0..3  (N quarter)

    // T1: bijective XCD swizzle of the (x,y) plane (nwg % 8 == 0 all modes)
    const int gx   = gridDim.x;
    const int nwg  = gx * gridDim.y;
    const int bid0 = blockIdx.y * gx + blockIdx.x;
    const int bid  = ((nwg & 7) == 0) ? ((bid0 & 7) * (nwg >> 3) + (bid0 >> 3))
                                      : bid0;
    const int bm = bid / gx;
    const int bn = bid % gx;
    const int z  = blockIdx.z;

    const unsigned short* Ap = A;
    const unsigned short* Bp = B;
    if (MODE == 2) { Ap += (long)z * LQN * DDIM; Bp += (long)z * LKN * DDIM; }
    if (MODE == 3) { Ap += (long)z * LQN * LKN;  Bp += (long)z * DDIM * LKN; }

    // staging: thread t covers rows (t>>2) and (t>>2)+128.
    // T2 source pre-swizzle: k-chunk = (t&3) ^ ((t>>3)&3)  [chunk = 8 shorts].
    // LDS phys chunk (row, kc) then holds logical (row, kc ^ ((row>>1)&3)):
    // valid for all 4 regions since every region base row is = 0 mod 8.
    const int srow = t >> 2;             // 0..127
    const int skk  = ((t & 3) ^ ((t >> 3) & 3)) * 8;
    const unsigned short* ga0 = Ap + (long)(bm * 256 + srow) * LDA + skk;
    const unsigned short* ga1 = ga0 + 128L * LDA;
    const unsigned short* gb0 = Bp + (long)(bn * 256 + srow) * LDB + skk;
    const unsigned short* gb1 = gb0 + 128L * LDB;
    const int woff = wave * 512;         // wave-uniform LDS chunk (shorts)

    f32x4 acc[8][4];
    #pragma unroll
    for (int i = 0; i < 8; ++i)
        #pragma unroll
        for (int j = 0; j < 4; ++j)
            acc[i][j] = (f32x4)(0.0f);

    const int quad = lane >> 4;
    const int l15  = lane & 15;
    // T2 read-side: same XOR. row = (wm*128|wn*64) + {i,j}*16 + l15, and
    // (row>>1)&3 == (l15>>1)&3 because all other terms are 0 mod 8 rows.
    const int qoff = (quad ^ ((l15 >> 1) & 3)) * 8;

    // stage K-tile kt into buffer bi (4 vmcnt events per wave)
#define STAGE(bi, kt) do {                                              \
        unsigned short* sb = &lds[(bi) * 16384];                        \
        const int ko = (kt) * 32;                                       \
        gl2lds16(ga0 + ko, sb + woff);                                  \
        gl2lds16(ga1 + ko, sb + 4096  + woff);                          \
        gl2lds16(gb0 + ko, sb + 8192  + woff);                          \
        gl2lds16(gb1 + ko, sb + 12288 + woff);                          \
    } while (0)

    // prologue: tiles 0 and 1 in flight; confirm tile 0 (4 oldest of 8)
    STAGE(0, 0);
    STAGE(1, 1);
    asm volatile("s_waitcnt vmcnt(4)" ::: "memory");
    __builtin_amdgcn_s_barrier();

    int cb = 0;
    for (int tt = 0; tt < NT; ++tt) {
        const int nb = (cb + 2 >= 3) ? (cb - 1) : (cb + 2);
        const bool st = (tt + 2 < NT);
        if (st) STAGE(nb, tt + 2);       // buffer nb last read in iter tt-1

        const unsigned short* sb = &lds[cb * 16384];
        bf16x8 af[8], bfv[4];
        #pragma unroll
        for (int j = 0; j < 4; ++j)
            bfv[j] = *(const bf16x8*)&sb[8192 + (wn * 64 + j * 16 + l15) * 32 + qoff];
        #pragma unroll
        for (int i = 0; i < 8; ++i)
            af[i] = *(const bf16x8*)&sb[(wm * 128 + i * 16 + l15) * 32 + qoff];

        __builtin_amdgcn_s_setprio(1);
        #pragma unroll
        for (int i = 0; i < 8; ++i)
            #pragma unroll
            for (int j = 0; j < 4; ++j)
                acc[i][j] = __builtin_amdgcn_mfma_f32_16x16x32_bf16(
                    af[i], bfv[j], acc[i][j], 0, 0, 0);
        __builtin_amdgcn_s_setprio(0);

        // confirm tile tt+1 (my wave's 4 oldest); tile tt+2 stays in flight
        if (st) asm volatile("s_waitcnt vmcnt(4)" ::: "memory");
        else    asm volatile("s_waitcnt vmcnt(0)" ::: "memory");
        __builtin_amdgcn_s_barrier();
        cb = (cb + 1 >= 3) ? 0 : (cb + 1);
    }
#undef STAGE

    // epilogue: C/D layout col=lane&15, row=quad*4+r  [measured m89/m91]
    #pragma unroll
    for (int i = 0; i < 8; ++i) {
        #pragma unroll
        for (int j = 0; j < 4; ++j) {
            const int grow = bm * 256 + wm * 128 + i * 16 + quad * 4;
            const int gcol = bn * 256 + wn * 64 + j * 16 + l15;
            if (MODE == 0) {
                const float bc = bias[gcol];
                #pragma unroll
                for (int r = 0; r < 4; ++r)
                    ((unsigned short*)out)[(long)(grow + r) * DDIM + gcol] =
                        f2bf(acc[i][j][r] + bc);
            } else if (MODE == 1) {
                const int b2 = gcol >> 11;        // in-group batch
                const int lk = gcol & 2047;
                #pragma unroll
                for (int r = 0; r < 4; ++r) {
                    const float bc = bias[grow + r];
                    ((unsigned short*)out)[(long)b2 * DDIM * LKN +
                                           (long)(grow + r) * LKN + lk] =
                        f2bf(acc[i][j][r] + bc);
                }
            } else if (MODE == 2) {
                const int mv = mask[z * LKN + gcol];
                #pragma unroll
                for (int r = 0; r < 4; ++r) {
                    float v = acc[i][j][r] * 0.03125f;   // 1/sqrt(1024)
                    if (mv == 0) v = -1e9f;
                    ((float*)out)[(long)z * LQN * LKN +
                                  (long)(grow + r) * LKN + gcol] = v;
                }
            } else {
                #pragma unroll
                for (int r = 0; r < 4; ++r)
                    ((float*)out)[(long)z * LQN * DDIM +
                                  (long)(grow + r) * DDIM + gcol] = acc[i][j][r];
            }
        }
    }
}

// in-place f32 row softmax over LKN scores; one block (256 thr) per row.
// Also emits bf16 copy (Pb) for the O-GEMM.
__global__ __launch_bounds__(256)
void softmax_rows(float* __restrict__ P, unsigned short* __restrict__ Pb)
{
    const int t = threadIdx.x;
    const long base = (long)blockIdx.x * LKN + t * 8;

    float4 r0 = *(const float4*)&P[base];
    float4 r1 = *(const float4*)&P[base + 4];
    float v[8] = { r0.x, r0.y, r0.z, r0.w, r1.x, r1.y, r1.z, r1.w };

    float m = -3.0e38f;
    #pragma unroll
    for (int i = 0; i < 8; ++i) m = fmaxf(m, v[i]);
    #pragma unroll
    for (int off = 32; off >= 1; off >>= 1) m = fmaxf(m, __shfl_xor(m, off, 64));
    __shared__ float redm[4];
    if ((t & 63) == 0) redm[t >> 6] = m;
    __syncthreads();
    m = fmaxf(fmaxf(redm[0], redm[1]), fmaxf(redm[2], redm[3]));

    float s = 0.0f;
    #pragma unroll
    for (int i = 0; i < 8; ++i) { v[i] = __expf(v[i] - m); s += v[i]; }
    #pragma unroll
    for (int off = 32; off >= 1; off >>= 1) s += __shfl_xor(s, off, 64);
    __shared__ float reds[4];
    if ((t & 63) == 0) reds[t >> 6] = s;
    __syncthreads();
    s = reds[0] + reds[1] + reds[2] + reds[3];

    const float inv = 1.0f / s;   // s >= 1 always (max element contributes 1)
    r0.x = v[0] * inv; r0.y = v[1] * inv; r0.z = v[2] * inv; r0.w = v[3] * inv;
    r1.x = v[4] * inv; r1.y = v[5] * inv; r1.z = v[6] * inv; r1.w = v[7] * inv;
    *(float4*)&P[base]     = r0;
    *(float4*)&P[base + 4] = r1;

    bf16x8 pb;
    pb[0] = (short)f2bf(r0.x); pb[1] = (short)f2bf(r0.y);
    pb[2] = (short)f2bf(r0.z); pb[3] = (short)f2bf(r0.w);
    pb[4] = (short)f2bf(r1.x); pb[5] = (short)f2bf(r1.y);
    pb[6] = (short)f2bf(r1.z); pb[7] = (short)f2bf(r1.w);
    *(bf16x8*)&Pb[base] = pb;
}

extern "C" void kernel_launch(void* const* d_in, const int* in_sizes, int n_in,
                              void* d_out, int out_size, void* d_ws, size_t ws_size,
                              hipStream_t stream)
{
    (void)in_sizes; (void)n_in; (void)out_size;

    const float* key   = (const float*)d_in[0];
    const float* query = (const float*)d_in[1];
    const int*   mask  = (const int*)d_in[2];
    const float* Wq    = (const float*)d_in[3];
    const float* bq    = (const float*)d_in[4];
    const float* Wk    = (const float*)d_in[5];
    const float* bk    = (const float*)d_in[6];
    const float* Wv    = (const float*)d_in[7];
    const float* bv    = (const float*)d_in[8];

    float* outO = (float*)d_out;                          // [B,LQ,D]  f32
    float* outP = outO + (size_t)BBAT * LQN * DDIM;       // [B,LQ,LK] f32

    // fixed workspace: bf16 weights, 3 x 2 MiB
    unsigned short* Wqb  = (unsigned short*)d_ws;
    unsigned short* Wkb  = Wqb + (size_t)DDIM * DDIM;
    unsigned short* Wvb  = Wkb + (size_t)DDIM * DDIM;
    unsigned short* gbuf = Wvb + (size_t)DDIM * DDIM;

    // per-batch: regionA (qc+kc, later overlaid by Pb) = LQN*LKN shorts (8 MiB)
    //            + Qp + Kp + Vt = 3 * LQN*DDIM shorts (12 MiB)  => 20 MiB
    const size_t fixed = (size_t)3 * DDIM * DDIM * sizeof(unsigned short);
    const size_t perB  = ((size_t)LQN * LKN + (size_t)3 * LQN * DDIM) *
                         sizeof(unsigned short);
    size_t avail = (ws_size > fixed) ? (ws_size - fixed) : 0;
    int g = (int)(avail / perB);
    if (g > BBAT) g = BBAT;
    if (g < 1)    g = 1;

    dim3 blk(256, 1, 1);
    dim3 gblk(512, 1, 1);

    // weights -> bf16 (once)
    cast_bf16<<<dim3(512, 1, 1), blk, 0, stream>>>(Wq, Wqb, (long)DDIM * DDIM / 8);
    cast_bf16<<<dim3(512, 1, 1), blk, 0, stream>>>(Wk, Wkb, (long)DDIM * DDIM / 8);
    cast_bf16<<<dim3(512, 1, 1), blk, 0, stream>>>(Wv, Wvb, (long)DDIM * DDIM / 8);

    for (int b0 = 0; b0 < BBAT; b0 += g) {
        const int gl = (BBAT - b0 < g) ? (BBAT - b0) : g;

        unsigned short* regionA = gbuf;                          // gl * 4Mi shorts
        unsigned short* qc = regionA;                            // [gl*LQ, D] bf16
        unsigned short* kc = regionA + (size_t)gl * LQN * DDIM;  // [gl*LK, D] bf16
        unsigned short* Pb = regionA;                            // [gl,LQ,LK] bf16 (overlays qc/kc)
        unsigned short* Qp = regionA + (size_t)gl * LQN * LKN;   // [gl*LQ, D] bf16
        unsigned short* Kp = Qp + (size_t)gl * LQN * DDIM;       // [gl*LK, D] bf16
        unsigned short* Vt = Kp + (size_t)gl * LKN * DDIM;       // [gl, D, LK] bf16

        // inputs -> bf16
        cast_bf16<<<dim3(2048, 1, 1), blk, 0, stream>>>(
            query + (size_t)b0 * LQN * DDIM, qc, (long)gl * LQN * DDIM / 8);
        cast_bf16<<<dim3(2048, 1, 1), blk, 0, stream>>>(
            key + (size_t)b0 * LKN * DDIM, kc, (long)gl * LKN * DDIM / 8);

        // Qp = qc*Wq^T + bq   (M=gl*2048, N=1024, K=1024)
        gemm_nt<0><<<dim3(4, gl * 8, 1), gblk, 0, stream>>>(qc, Wqb, bq, nullptr, Qp);

        // Kp = kc*Wk^T + bk
        gemm_nt<0><<<dim3(4, gl * 8, 1), gblk, 0, stream>>>(kc, Wkb, bk, nullptr, Kp);

        // Vt[z][d][lk] = Wv*Kp^T + bv   (M=1024, N=gl*2048, K=1024)
        gemm_nt<1><<<dim3(gl * 8, 4, 1), gblk, 0, stream>>>(Wvb, Kp, bv, nullptr, Vt);

        // S[z] = Qp[z]*Kp[z]^T * scale, mask fill  (per z: 2048x2048, K=1024)
        gemm_nt<2><<<dim3(8, 8, gl), gblk, 0, stream>>>(
            Qp, Kp, nullptr, mask + (size_t)b0 * LKN,
            outP + (size_t)b0 * LQN * LKN);

        // softmax rows in place (f32) + bf16 copy for the O-GEMM
        softmax_rows<<<dim3(gl * LQN, 1, 1), blk, 0, stream>>>(
            outP + (size_t)b0 * LQN * LKN, Pb);

        // O[z] = Pb[z]*Vt[z]^T   (per z: M=2048, N=1024, K=2048)
        gemm_nt<3><<<dim3(4, 8, gl), gblk, 0, stream>>>(
            Pb, Vt, nullptr, nullptr, outO + (size_t)b0 * LQN * DDIM);
    }
}

// Round 5
// 607.278 us; speedup vs baseline: 1.4076x; 1.0078x over previous
//
#include <hip/hip_runtime.h>
#include <cstdint>

// Problem constants (B, LQ, LK, D fixed by the reference)
#define DDIM 1024
#define LQN  2048
#define LKN  2048
#define BBAT 8

// ROUND-8: fine-phase counted-vmcnt pipeline (T3+T4 proper) + z-folded T1.
//  - 4 LDS dbufs (128 KiB), prefetch depth 3, boundary vmcnt(8) (never 0
//    mid-loop; tail 8->4->0). Confirmed: coarse 2-deep counted vmcnt (R3/R4)
//    underperforms per m196; depth was ~1 iter vs ~900cy HBM latency.
//  - each K-step (BK=32) split into 2 phases of 16 MFMA:
//    {ds_read subtile | issue 2 gl_lds} -> barrier -> lgkmcnt(0) ->
//    setprio(1) -> 16 MFMA -> setprio(0); boundary: vmcnt(N) -> barrier.
//  - z folded into XCD swizzle: each XCD processes one batch's panels
//    (4-5 MB working set vs 4 MiB per-XCD L2).
//  - R4 source-pre-swizzle kept (neutral; SQ_LDS_BANK_CONFLICT=2^23 was a
//    saturated artifact, read pattern was already uniform).
//  - numerics identical to R1-R4 (absmax 4.88e-4).

typedef short bf16x8 __attribute__((ext_vector_type(8)));
typedef float f32x4  __attribute__((ext_vector_type(4)));

__device__ __forceinline__ unsigned short f2bf(float f) {
    union { float f; unsigned int i; } x; x.f = f;
    unsigned int r = (x.i + 0x7fffu + ((x.i >> 16) & 1u)) >> 16;  // RNE
    return (unsigned short)r;
}
__device__ __forceinline__ bf16x8 cvt8(const float* p) {
    float4 x0 = *(const float4*)p;
    float4 x1 = *(const float4*)(p + 4);
    bf16x8 r;
    r[0] = (short)f2bf(x0.x); r[1] = (short)f2bf(x0.y);
    r[2] = (short)f2bf(x0.z); r[3] = (short)f2bf(x0.w);
    r[4] = (short)f2bf(x1.x); r[5] = (short)f2bf(x1.y);
    r[6] = (short)f2bf(x1.z); r[7] = (short)f2bf(x1.w);
    return r;
}

// async global->LDS, 16B per lane. LDS dst is wave-uniform base; HW writes
// lane i at base + i*16. Global src is per-lane (enables source pre-swizzle).
__device__ __forceinline__ void gl2lds16(const void* g, void* l) {
    __builtin_amdgcn_global_load_lds(
        reinterpret_cast<const __attribute__((address_space(1))) void*>(
            reinterpret_cast<uintptr_t>(g)),
        reinterpret_cast<__attribute__((address_space(3))) void*>(
            (unsigned)reinterpret_cast<uintptr_t>(l)),
        16, 0, 0);
}

// f32 -> bf16 elementwise cast, 8 elems/thread, grid-stride
__global__ __launch_bounds__(256)
void cast_bf16(const float* __restrict__ in, unsigned short* __restrict__ out,
               long n8)
{
    long i = (long)blockIdx.x * blockDim.x + threadIdx.x;
    const long stride = (long)gridDim.x * blockDim.x;
    for (; i < n8; i += stride)
        *(bf16x8*)(out + i * 8) = cvt8(in + i * 8);
}

// Pure-bf16 NT GEMM: C[M,N] = A[M,K] * B[N,K]^T. 256x256 tile, BK=32,
// 512 thr = 8 waves (2M x 4N), wave tile 128x64 via 8x4 mfma_f32_16x16x32_bf16.
// MODE 0: Qp/Kp = Xb*Wb^T + b   out bf16, bias[col]
// MODE 1: Vt = Wvb*Kp^T + bv    out bf16 [b2][row][lk], bias[row]
// MODE 2: S = Qp*Kp^T *s, mask  out f32, batched via z
// MODE 3: O = Pb*Vt^T           out f32, batched via z
template<int MODE>
__global__ __launch_bounds__(512)
void gemm_nt(const unsigned short* __restrict__ A,
             const unsigned short* __restrict__ B,
             const float* __restrict__ bias,
             const int* __restrict__ mask,
             void* __restrict__ out)
{
    constexpr int K   = (MODE == 3) ? LKN : DDIM;
    constexpr int LDA = K;
    constexpr int LDB = K;
    constexpr int NT  = K / 32;          // 32 (mode3) or 16 (others)

    // 4 dbufs, each: A[256][32] (8192 shorts) + B[256][32] (8192 shorts)
    __shared__ unsigned short lds[4 * 16384];   // 128 KiB

    const int t    = threadIdx.x;
    const int lane = t & 63;
    const int wave = t >> 6;             // 0..7
    const int wm   = wave >> 2;          // 0..1  (M half)
    const int wn   = wave & 3;           // 0..3  (N quarter)

    // T1 (z-folded): bijective XCD swizzle over the FULL grid. nwg%8==0 in
    // all modes; chunk = nwg/8 equals one z-plane for modes 2/3 -> each XCD
    // streams one batch's panels (fits its 4 MiB L2).
    const int gx  = gridDim.x;
    const int gy  = gridDim.y;
    const int nwg = gx * gy * gridDim.z;
    int lin = (blockIdx.z * gy + blockIdx.y) * gx + blockIdx.x;
    if ((nwg & 7) == 0) lin = (lin & 7) * (nwg >> 3) + (lin >> 3);
    const int plane = gx * gy;
    const int z   = lin / plane;
    const int rem = lin - z * plane;
    const int bm  = rem / gx;
    const int bn  = rem - (rem / gx) * gx;

    const unsigned short* Ap = A;
    const unsigned short* Bp = B;
    if (MODE == 2) { Ap += (long)z * LQN * DDIM; Bp += (long)z * LKN * DDIM; }
    if (MODE == 3) { Ap += (long)z * LQN * LKN;  Bp += (long)z * DDIM * LKN; }

    // staging: thread t covers rows (t>>2) and (t>>2)+128.
    // source pre-swizzle: phys k-chunk (t&3) holds logical chunk
    // (t&3) ^ ((row>>1)&3)  [chunk = 8 shorts = 16B]
    const int srow = t >> 2;             // 0..127
    const int skk  = ((t & 3) ^ ((t >> 3) & 3)) * 8;
    const unsigned short* ga0 = Ap + (long)(bm * 256 + srow) * LDA + skk;
    const unsigned short* ga1 = ga0 + 128L * LDA;
    const unsigned short* gb0 = Bp + (long)(bn * 256 + srow) * LDB + skk;
    const unsigned short* gb1 = gb0 + 128L * LDB;
    const int woff = wave * 512;         // wave-uniform LDS chunk (shorts)

    f32x4 acc[8][4];
    #pragma unroll
    for (int i = 0; i < 8; ++i)
        #pragma unroll
        for (int j = 0; j < 4; ++j)
            acc[i][j] = (f32x4)(0.0f);

    const int quad = lane >> 4;
    const int l15  = lane & 15;
    // read-side of the source pre-swizzle (row ~ l15 mod 8)
    const int qoff = (quad ^ ((l15 >> 1) & 3)) * 8;

    // stage full K-tile kt into dbuf bi (4 vmcnt events per wave)
#define STAGE(bi, kt) do {                                              \
        unsigned short* sbw = &lds[(bi) * 16384];                       \
        const int ko = (kt) * 32;                                       \
        gl2lds16(ga0 + ko, sbw + woff);                                 \
        gl2lds16(ga1 + ko, sbw + 4096  + woff);                         \
        gl2lds16(gb0 + ko, sbw + 8192  + woff);                         \
        gl2lds16(gb1 + ko, sbw + 12288 + woff);                         \
    } while (0)

    // prologue: tiles 0,1,2 in flight (12 loads); confirm tile 0 (4 oldest)
    STAGE(0, 0);
    STAGE(1, 1);
    STAGE(2, 2);
    asm volatile("s_waitcnt vmcnt(8)" ::: "memory");
    __builtin_amdgcn_s_barrier();

    for (int tt = 0; tt < NT; ++tt) {
        const unsigned short* sb = &lds[(tt & 3) * 16384];
        unsigned short* nbuf = &lds[((tt + 3) & 3) * 16384];
        const int  ko = (tt + 3) * 32;
        const bool st = (tt + 3 < NT);

        // ---- phase A: reads {B n0-3, A m0-3} | stage A-halves of t+3 ----
        bf16x8 bfv[4], af[4];
        #pragma unroll
        for (int j = 0; j < 4; ++j)
            bfv[j] = *(const bf16x8*)&sb[8192 + (wn * 64 + j * 16 + l15) * 32 + qoff];
        #pragma unroll
        for (int i = 0; i < 4; ++i)
            af[i] = *(const bf16x8*)&sb[(wm * 128 + i * 16 + l15) * 32 + qoff];
        if (st) {
            gl2lds16(ga0 + ko, nbuf + woff);
            gl2lds16(ga1 + ko, nbuf + 4096 + woff);
        }
        __builtin_amdgcn_s_barrier();
        asm volatile("s_waitcnt lgkmcnt(0)" ::: "memory");
        __builtin_amdgcn_s_setprio(1);
        #pragma unroll
        for (int i = 0; i < 4; ++i)
            #pragma unroll
            for (int j = 0; j < 4; ++j)
                acc[i][j] = __builtin_amdgcn_mfma_f32_16x16x32_bf16(
                    af[i], bfv[j], acc[i][j], 0, 0, 0);
        __builtin_amdgcn_s_setprio(0);

        // ---- phase B: reads {A m4-7} | stage B-halves of t+3 ----
        bf16x8 af2[4];
        #pragma unroll
        for (int i = 0; i < 4; ++i)
            af2[i] = *(const bf16x8*)&sb[(wm * 128 + 64 + i * 16 + l15) * 32 + qoff];
        if (st) {
            gl2lds16(gb0 + ko, nbuf + 8192 + woff);
            gl2lds16(gb1 + ko, nbuf + 12288 + woff);
        }
        __builtin_amdgcn_s_barrier();
        asm volatile("s_waitcnt lgkmcnt(0)" ::: "memory");
        __builtin_amdgcn_s_setprio(1);
        #pragma unroll
        for (int i = 0; i < 4; ++i)
            #pragma unroll
            for (int j = 0; j < 4; ++j)
                acc[i + 4][j] = __builtin_amdgcn_mfma_f32_16x16x32_bf16(
                    af2[i], bfv[j], acc[i + 4][j], 0, 0, 0);
        __builtin_amdgcn_s_setprio(0);

        // ---- boundary: confirm tile tt+1; keep tt+2/tt+3 in flight ----
        if (tt < NT - 3)       asm volatile("s_waitcnt vmcnt(8)" ::: "memory");
        else if (tt == NT - 3) asm volatile("s_waitcnt vmcnt(4)" ::: "memory");
        else                   asm volatile("s_waitcnt vmcnt(0)" ::: "memory");
        __builtin_amdgcn_s_barrier();
    }
#undef STAGE

    // epilogue: C/D layout col=lane&15, row=quad*4+r  [measured m89/m91]
    #pragma unroll
    for (int i = 0; i < 8; ++i) {
        #pragma unroll
        for (int j = 0; j < 4; ++j) {
            const int grow = bm * 256 + wm * 128 + i * 16 + quad * 4;
            const int gcol = bn * 256 + wn * 64 + j * 16 + l15;
            if (MODE == 0) {
                const float bc = bias[gcol];
                #pragma unroll
                for (int r = 0; r < 4; ++r)
                    ((unsigned short*)out)[(long)(grow + r) * DDIM + gcol] =
                        f2bf(acc[i][j][r] + bc);
            } else if (MODE == 1) {
                const int b2 = gcol >> 11;        // in-group batch
                const int lk = gcol & 2047;
                #pragma unroll
                for (int r = 0; r < 4; ++r) {
                    const float bc = bias[grow + r];
                    ((unsigned short*)out)[(long)b2 * DDIM * LKN +
                                           (long)(grow + r) * LKN + lk] =
                        f2bf(acc[i][j][r] + bc);
                }
            } else if (MODE == 2) {
                const int mv = mask[z * LKN + gcol];
                #pragma unroll
                for (int r = 0; r < 4; ++r) {
                    float v = acc[i][j][r] * 0.03125f;   // 1/sqrt(1024)
                    if (mv == 0) v = -1e9f;
                    ((float*)out)[(long)z * LQN * LKN +
                                  (long)(grow + r) * LKN + gcol] = v;
                }
            } else {
                #pragma unroll
                for (int r = 0; r < 4; ++r)
                    ((float*)out)[(long)z * LQN * DDIM +
                                  (long)(grow + r) * DDIM + gcol] = acc[i][j][r];
            }
        }
    }
}

// in-place f32 row softmax over LKN scores; one block (256 thr) per row.
// Also emits bf16 copy (Pb) for the O-GEMM.
__global__ __launch_bounds__(256)
void softmax_rows(float* __restrict__ P, unsigned short* __restrict__ Pb)
{
    const int t = threadIdx.x;
    const long base = (long)blockIdx.x * LKN + t * 8;

    float4 r0 = *(const float4*)&P[base];
    float4 r1 = *(const float4*)&P[base + 4];
    float v[8] = { r0.x, r0.y, r0.z, r0.w, r1.x, r1.y, r1.z, r1.w };

    float m = -3.0e38f;
    #pragma unroll
    for (int i = 0; i < 8; ++i) m = fmaxf(m, v[i]);
    #pragma unroll
    for (int off = 32; off >= 1; off >>= 1) m = fmaxf(m, __shfl_xor(m, off, 64));
    __shared__ float redm[4];
    if ((t & 63) == 0) redm[t >> 6] = m;
    __syncthreads();
    m = fmaxf(fmaxf(redm[0], redm[1]), fmaxf(redm[2], redm[3]));

    float s = 0.0f;
    #pragma unroll
    for (int i = 0; i < 8; ++i) { v[i] = __expf(v[i] - m); s += v[i]; }
    #pragma unroll
    for (int off = 32; off >= 1; off >>= 1) s += __shfl_xor(s, off, 64);
    __shared__ float reds[4];
    if ((t & 63) == 0) reds[t >> 6] = s;
    __syncthreads();
    s = reds[0] + reds[1] + reds[2] + reds[3];

    const float inv = 1.0f / s;   // s >= 1 always (max element contributes 1)
    r0.x = v[0] * inv; r0.y = v[1] * inv; r0.z = v[2] * inv; r0.w = v[3] * inv;
    r1.x = v[4] * inv; r1.y = v[5] * inv; r1.z = v[6] * inv; r1.w = v[7] * inv;
    *(float4*)&P[base]     = r0;
    *(float4*)&P[base + 4] = r1;

    bf16x8 pb;
    pb[0] = (short)f2bf(r0.x); pb[1] = (short)f2bf(r0.y);
    pb[2] = (short)f2bf(r0.z); pb[3] = (short)f2bf(r0.w);
    pb[4] = (short)f2bf(r1.x); pb[5] = (short)f2bf(r1.y);
    pb[6] = (short)f2bf(r1.z); pb[7] = (short)f2bf(r1.w);
    *(bf16x8*)&Pb[base] = pb;
}

extern "C" void kernel_launch(void* const* d_in, const int* in_sizes, int n_in,
                              void* d_out, int out_size, void* d_ws, size_t ws_size,
                              hipStream_t stream)
{
    (void)in_sizes; (void)n_in; (void)out_size;

    const float* key   = (const float*)d_in[0];
    const float* query = (const float*)d_in[1];
    const int*   mask  = (const int*)d_in[2];
    const float* Wq    = (const float*)d_in[3];
    const float* bq    = (const float*)d_in[4];
    const float* Wk    = (const float*)d_in[5];
    const float* bk    = (const float*)d_in[6];
    const float* Wv    = (const float*)d_in[7];
    const float* bv    = (const float*)d_in[8];

    float* outO = (float*)d_out;                          // [B,LQ,D]  f32
    float* outP = outO + (size_t)BBAT * LQN * DDIM;       // [B,LQ,LK] f32

    // fixed workspace: bf16 weights, 3 x 2 MiB
    unsigned short* Wqb  = (unsigned short*)d_ws;
    unsigned short* Wkb  = Wqb + (size_t)DDIM * DDIM;
    unsigned short* Wvb  = Wkb + (size_t)DDIM * DDIM;
    unsigned short* gbuf = Wvb + (size_t)DDIM * DDIM;

    // per-batch: regionA (qc+kc, later overlaid by Pb) = LQN*LKN shorts (8 MiB)
    //            + Qp + Kp + Vt = 3 * LQN*DDIM shorts (12 MiB)  => 20 MiB
    const size_t fixed = (size_t)3 * DDIM * DDIM * sizeof(unsigned short);
    const size_t perB  = ((size_t)LQN * LKN + (size_t)3 * LQN * DDIM) *
                         sizeof(unsigned short);
    size_t avail = (ws_size > fixed) ? (ws_size - fixed) : 0;
    int g = (int)(avail / perB);
    if (g > BBAT) g = BBAT;
    if (g < 1)    g = 1;

    dim3 blk(256, 1, 1);
    dim3 gblk(512, 1, 1);

    // weights -> bf16 (once)
    cast_bf16<<<dim3(512, 1, 1), blk, 0, stream>>>(Wq, Wqb, (long)DDIM * DDIM / 8);
    cast_bf16<<<dim3(512, 1, 1), blk, 0, stream>>>(Wk, Wkb, (long)DDIM * DDIM / 8);
    cast_bf16<<<dim3(512, 1, 1), blk, 0, stream>>>(Wv, Wvb, (long)DDIM * DDIM / 8);

    for (int b0 = 0; b0 < BBAT; b0 += g) {
        const int gl = (BBAT - b0 < g) ? (BBAT - b0) : g;

        unsigned short* regionA = gbuf;                          // gl * 4Mi shorts
        unsigned short* qc = regionA;                            // [gl*LQ, D] bf16
        unsigned short* kc = regionA + (size_t)gl * LQN * DDIM;  // [gl*LK, D] bf16
        unsigned short* Pb = regionA;                            // [gl,LQ,LK] bf16 (overlays qc/kc)
        unsigned short* Qp = regionA + (size_t)gl * LQN * LKN;   // [gl*LQ, D] bf16
        unsigned short* Kp = Qp + (size_t)gl * LQN * DDIM;       // [gl*LK, D] bf16
        unsigned short* Vt = Kp + (size_t)gl * LKN * DDIM;       // [gl, D, LK] bf16

        // inputs -> bf16
        cast_bf16<<<dim3(2048, 1, 1), blk, 0, stream>>>(
            query + (size_t)b0 * LQN * DDIM, qc, (long)gl * LQN * DDIM / 8);
        cast_bf16<<<dim3(2048, 1, 1), blk, 0, stream>>>(
            key + (size_t)b0 * LKN * DDIM, kc, (long)gl * LKN * DDIM / 8);

        // Qp = qc*Wq^T + bq   (M=gl*2048, N=1024, K=1024)
        gemm_nt<0><<<dim3(4, gl * 8, 1), gblk, 0, stream>>>(qc, Wqb, bq, nullptr, Qp);

        // Kp = kc*Wk^T + bk
        gemm_nt<0><<<dim3(4, gl * 8, 1), gblk, 0, stream>>>(kc, Wkb, bk, nullptr, Kp);

        // Vt[z][d][lk] = Wv*Kp^T + bv   (M=1024, N=gl*2048, K=1024)
        gemm_nt<1><<<dim3(gl * 8, 4, 1), gblk, 0, stream>>>(Wvb, Kp, bv, nullptr, Vt);

        // S[z] = Qp[z]*Kp[z]^T * scale, mask fill  (per z: 2048x2048, K=1024)
        gemm_nt<2><<<dim3(8, 8, gl), gblk, 0, stream>>>(
            Qp, Kp, nullptr, mask + (size_t)b0 * LKN,
            outP + (size_t)b0 * LQN * LKN);

        // softmax rows in place (f32) + bf16 copy for the O-GEMM
        softmax_rows<<<dim3(gl * LQN, 1, 1), blk, 0, stream>>>(
            outP + (size_t)b0 * LQN * LKN, Pb);

        // O[z] = Pb[z]*Vt[z]^T   (per z: M=2048, N=1024, K=2048)
        gemm_nt<3><<<dim3(4, 8, gl), gblk, 0, stream>>>(
            Pb, Vt, nullptr, nullptr, outO + (size_t)b0 * LQN * DDIM);
    }
}

// Round 7
// 602.648 us; speedup vs baseline: 1.4184x; 1.0077x over previous
//
#include <hip/hip_runtime.h>
#include <cstdint>

// Problem constants (B, LQ, LK, D fixed by the reference)
#define DDIM 1024
#define LQN  2048
#define LKN  2048
#define BBAT 8

// ROUND-10 (= R9 resubmit; R9 bench was an infra failure, no signal).
// Vectorized LDS-transpose epilogues (dwordx4 stores, full lines).
//  - R1 evidence: mode0 (34 GF) == mode2/3 (69 GF) duration -> epilogue-bound.
//  - old: 128 scalar stores/thread, 64-B (f32) / 32-B (bf16) segments.
//  - new: per-wave LDS transpose (padded pitch, <=2-way bank alias = free),
//    then dwordx4 stores: 256 B contiguous per 4-lane group (f32) /
//    128 B per 8-lane group (bf16). Bias/mask/scale before transpose ->
//    numerics bit-identical (absmax 4.88e-4).
//  - K-loop identical to R5 (4 dbufs, depth-3, counted vmcnt, 2-phase).
//  - audited: LDS bounds, barrier uniformity, OOB stores, staging drain. OK.

typedef short bf16x8 __attribute__((ext_vector_type(8)));
typedef float f32x4  __attribute__((ext_vector_type(4)));

__device__ __forceinline__ unsigned short f2bf(float f) {
    union { float f; unsigned int i; } x; x.f = f;
    unsigned int r = (x.i + 0x7fffu + ((x.i >> 16) & 1u)) >> 16;  // RNE
    return (unsigned short)r;
}
__device__ __forceinline__ bf16x8 cvt8(const float* p) {
    float4 x0 = *(const float4*)p;
    float4 x1 = *(const float4*)(p + 4);
    bf16x8 r;
    r[0] = (short)f2bf(x0.x); r[1] = (short)f2bf(x0.y);
    r[2] = (short)f2bf(x0.z); r[3] = (short)f2bf(x0.w);
    r[4] = (short)f2bf(x1.x); r[5] = (short)f2bf(x1.y);
    r[6] = (short)f2bf(x1.z); r[7] = (short)f2bf(x1.w);
    return r;
}

// async global->LDS, 16B per lane. LDS dst is wave-uniform base; HW writes
// lane i at base + i*16. Global src is per-lane.
__device__ __forceinline__ void gl2lds16(const void* g, void* l) {
    __builtin_amdgcn_global_load_lds(
        reinterpret_cast<const __attribute__((address_space(1))) void*>(
            reinterpret_cast<uintptr_t>(g)),
        reinterpret_cast<__attribute__((address_space(3))) void*>(
            (unsigned)reinterpret_cast<uintptr_t>(l)),
        16, 0, 0);
}

// f32 -> bf16 elementwise cast, 8 elems/thread, grid-stride
__global__ __launch_bounds__(256)
void cast_bf16(const float* __restrict__ in, unsigned short* __restrict__ out,
               long n8)
{
    long i = (long)blockIdx.x * blockDim.x + threadIdx.x;
    const long stride = (long)gridDim.x * blockDim.x;
    for (; i < n8; i += stride)
        *(bf16x8*)(out + i * 8) = cvt8(in + i * 8);
}

// Pure-bf16 NT GEMM: C[M,N] = A[M,K] * B[N,K]^T. 256x256 tile, BK=32,
// 512 thr = 8 waves (2M x 4N), wave tile 128x64 via 8x4 mfma_f32_16x16x32_bf16.
// MODE 0: Qp/Kp = Xb*Wb^T + b   out bf16, bias[col]
// MODE 1: Vt = Wvb*Kp^T + bv    out bf16 [b2][row][lk], bias[row]
// MODE 2: S = Qp*Kp^T *s, mask  out f32, batched via z
// MODE 3: O = Pb*Vt^T           out f32, batched via z
template<int MODE>
__global__ __launch_bounds__(512)
void gemm_nt(const unsigned short* __restrict__ A,
             const unsigned short* __restrict__ B,
             const float* __restrict__ bias,
             const int* __restrict__ mask,
             void* __restrict__ out)
{
    constexpr int K   = (MODE == 3) ? LKN : DDIM;
    constexpr int LDA = K;
    constexpr int LDB = K;
    constexpr int NT  = K / 32;

    // 4 dbufs, each: A[256][32] (8192 shorts) + B[256][32] (8192 shorts)
    __shared__ unsigned short lds[4 * 16384];   // 128 KiB

    const int t    = threadIdx.x;
    const int lane = t & 63;
    const int wave = t >> 6;             // 0..7
    const int wm   = wave >> 2;          // 0..1  (M half)
    const int wn   = wave & 3;           // 0..3  (N quarter)

    // T1 (z-folded): bijective XCD swizzle over the FULL grid (nwg%8==0).
    const int gx  = gridDim.x;
    const int gy  = gridDim.y;
    const int nwg = gx * gy * gridDim.z;
    int lin = (blockIdx.z * gy + blockIdx.y) * gx + blockIdx.x;
    if ((nwg & 7) == 0) lin = (lin & 7) * (nwg >> 3) + (lin >> 3);
    const int plane = gx * gy;
    const int z   = lin / plane;
    const int rem = lin - z * plane;
    const int bm  = rem / gx;
    const int bn  = rem - (rem / gx) * gx;

    const unsigned short* Ap = A;
    const unsigned short* Bp = B;
    if (MODE == 2) { Ap += (long)z * LQN * DDIM; Bp += (long)z * LKN * DDIM; }
    if (MODE == 3) { Ap += (long)z * LQN * LKN;  Bp += (long)z * DDIM * LKN; }

    // staging: thread t covers rows (t>>2) and (t>>2)+128; source pre-swizzle
    const int srow = t >> 2;             // 0..127
    const int skk  = ((t & 3) ^ ((t >> 3) & 3)) * 8;
    const unsigned short* ga0 = Ap + (long)(bm * 256 + srow) * LDA + skk;
    const unsigned short* ga1 = ga0 + 128L * LDA;
    const unsigned short* gb0 = Bp + (long)(bn * 256 + srow) * LDB + skk;
    const unsigned short* gb1 = gb0 + 128L * LDB;
    const int woff = wave * 512;         // wave-uniform LDS chunk (shorts)

    f32x4 acc[8][4];
    #pragma unroll
    for (int i = 0; i < 8; ++i)
        #pragma unroll
        for (int j = 0; j < 4; ++j)
            acc[i][j] = (f32x4)(0.0f);

    const int quad = lane >> 4;
    const int l15  = lane & 15;
    const int qoff = (quad ^ ((l15 >> 1) & 3)) * 8;   // read side of pre-swizzle

#define STAGE(bi, kt) do {                                              \
        unsigned short* sbw = &lds[(bi) * 16384];                       \
        const int ko = (kt) * 32;                                       \
        gl2lds16(ga0 + ko, sbw + woff);                                 \
        gl2lds16(ga1 + ko, sbw + 4096  + woff);                         \
        gl2lds16(gb0 + ko, sbw + 8192  + woff);                         \
        gl2lds16(gb1 + ko, sbw + 12288 + woff);                         \
    } while (0)

    // prologue: tiles 0,1,2 in flight (12 loads); confirm tile 0
    STAGE(0, 0);
    STAGE(1, 1);
    STAGE(2, 2);
    asm volatile("s_waitcnt vmcnt(8)" ::: "memory");
    __builtin_amdgcn_s_barrier();

    for (int tt = 0; tt < NT; ++tt) {
        const unsigned short* sb = &lds[(tt & 3) * 16384];
        unsigned short* nbuf = &lds[((tt + 3) & 3) * 16384];
        const int  ko = (tt + 3) * 32;
        const bool st = (tt + 3 < NT);

        // ---- phase A: reads {B n0-3, A m0-3} | stage A-halves of t+3 ----
        bf16x8 bfv[4], af[4];
        #pragma unroll
        for (int j = 0; j < 4; ++j)
            bfv[j] = *(const bf16x8*)&sb[8192 + (wn * 64 + j * 16 + l15) * 32 + qoff];
        #pragma unroll
        for (int i = 0; i < 4; ++i)
            af[i] = *(const bf16x8*)&sb[(wm * 128 + i * 16 + l15) * 32 + qoff];
        if (st) {
            gl2lds16(ga0 + ko, nbuf + woff);
            gl2lds16(ga1 + ko, nbuf + 4096 + woff);
        }
        __builtin_amdgcn_s_barrier();
        asm volatile("s_waitcnt lgkmcnt(0)" ::: "memory");
        __builtin_amdgcn_s_setprio(1);
        #pragma unroll
        for (int i = 0; i < 4; ++i)
            #pragma unroll
            for (int j = 0; j < 4; ++j)
                acc[i][j] = __builtin_amdgcn_mfma_f32_16x16x32_bf16(
                    af[i], bfv[j], acc[i][j], 0, 0, 0);
        __builtin_amdgcn_s_setprio(0);

        // ---- phase B: reads {A m4-7} | stage B-halves of t+3 ----
        bf16x8 af2[4];
        #pragma unroll
        for (int i = 0; i < 4; ++i)
            af2[i] = *(const bf16x8*)&sb[(wm * 128 + 64 + i * 16 + l15) * 32 + qoff];
        if (st) {
            gl2lds16(gb0 + ko, nbuf + 8192 + woff);
            gl2lds16(gb1 + ko, nbuf + 12288 + woff);
        }
        __builtin_amdgcn_s_barrier();
        asm volatile("s_waitcnt lgkmcnt(0)" ::: "memory");
        __builtin_amdgcn_s_setprio(1);
        #pragma unroll
        for (int i = 0; i < 4; ++i)
            #pragma unroll
            for (int j = 0; j < 4; ++j)
                acc[i + 4][j] = __builtin_amdgcn_mfma_f32_16x16x32_bf16(
                    af2[i], bfv[j], acc[i + 4][j], 0, 0, 0);
        __builtin_amdgcn_s_setprio(0);

        // ---- boundary: confirm tile tt+1; keep tt+2/tt+3 in flight ----
        if (tt < NT - 3)       asm volatile("s_waitcnt vmcnt(8)" ::: "memory");
        else if (tt == NT - 3) asm volatile("s_waitcnt vmcnt(4)" ::: "memory");
        else                   asm volatile("s_waitcnt vmcnt(0)" ::: "memory");
        __builtin_amdgcn_s_barrier();
    }
#undef STAGE

    // ---- epilogue: per-wave LDS transpose -> dwordx4 stores ----
    // After the final barrier all staging is drained; each wave uses a
    // PRIVATE scratch region, so no further barriers are needed.
    __builtin_amdgcn_sched_barrier(0);

    const int growB = bm * 256 + wm * 128;   // + i*16 + row
    const int gcolW = bn * 256 + wn * 64;    // + (0..63)

    if (MODE == 2 || MODE == 3) {
        // f32 path: scratch 16 x 68 f32 per wave (pitch 272 B, 16-B mult)
        float* tw = (float*)&lds[0] + wave * (16 * 68);
        int maskv[4];
        if (MODE == 2) {
            #pragma unroll
            for (int j = 0; j < 4; ++j)
                maskv[j] = mask[z * LKN + gcolW + j * 16 + l15];
        }
        #pragma unroll
        for (int i = 0; i < 8; ++i) {
            asm volatile("s_waitcnt lgkmcnt(0)" ::: "memory");
            __builtin_amdgcn_sched_barrier(0);
            #pragma unroll
            for (int j = 0; j < 4; ++j)
                #pragma unroll
                for (int r = 0; r < 4; ++r) {
                    float v = acc[i][j][r];
                    if (MODE == 2) {
                        v *= 0.03125f;              // 1/sqrt(1024)
                        if (maskv[j] == 0) v = -1e9f;
                    }
                    tw[(quad * 4 + r) * 68 + j * 16 + l15] = v;
                }
            asm volatile("s_waitcnt lgkmcnt(0)" ::: "memory");
            __builtin_amdgcn_sched_barrier(0);
            #pragma unroll
            for (int p = 0; p < 4; ++p) {
                const int row = p * 4 + quad;
                const int col = l15 * 4;
                f32x4 v4 = *(const f32x4*)&tw[row * 68 + col];
                float* op = (float*)out;
                long idx;
                if (MODE == 2)
                    idx = (long)z * LQN * LKN +
                          (long)(growB + i * 16 + row) * LKN + gcolW + col;
                else
                    idx = (long)z * LQN * DDIM +
                          (long)(growB + i * 16 + row) * DDIM + gcolW + col;
                *(f32x4*)&op[idx] = v4;
            }
        }
    } else {
        // bf16 path: scratch 16 x 72 shorts per wave (pitch 144 B, 16-B mult)
        unsigned short* tw = &lds[0] + wave * (16 * 72);
        float bc[4];
        if (MODE == 0) {
            #pragma unroll
            for (int j = 0; j < 4; ++j)
                bc[j] = bias[gcolW + j * 16 + l15];
        }
        const int b2  = (MODE == 1) ? (bn >> 3) : 0;
        const int lkW = (MODE == 1) ? ((bn & 7) * 256 + wn * 64) : 0;
        #pragma unroll
        for (int i = 0; i < 8; ++i) {
            asm volatile("s_waitcnt lgkmcnt(0)" ::: "memory");
            __builtin_amdgcn_sched_barrier(0);
            #pragma unroll
            for (int j = 0; j < 4; ++j)
                #pragma unroll
                for (int r = 0; r < 4; ++r) {
                    float b = (MODE == 0) ? bc[j]
                                          : bias[growB + i * 16 + quad * 4 + r];
                    tw[(quad * 4 + r) * 72 + j * 16 + l15] =
                        f2bf(acc[i][j][r] + b);
                }
            asm volatile("s_waitcnt lgkmcnt(0)" ::: "memory");
            __builtin_amdgcn_sched_barrier(0);
            #pragma unroll
            for (int p = 0; p < 2; ++p) {
                const int row = p * 8 + (lane >> 3);
                const int col = (lane & 7) * 8;
                bf16x8 v8 = *(const bf16x8*)&tw[row * 72 + col];
                unsigned short* op = (unsigned short*)out;
                long idx;
                if (MODE == 0)
                    idx = (long)(growB + i * 16 + row) * DDIM + gcolW + col;
                else
                    idx = (long)b2 * DDIM * LKN +
                          (long)(growB + i * 16 + row) * LKN + lkW + col;
                *(bf16x8*)&op[idx] = v8;
            }
        }
    }
}

// in-place f32 row softmax over LKN scores; one block (256 thr) per row.
// Also emits bf16 copy (Pb) for the O-GEMM.
__global__ __launch_bounds__(256)
void softmax_rows(float* __restrict__ P, unsigned short* __restrict__ Pb)
{
    const int t = threadIdx.x;
    const long base = (long)blockIdx.x * LKN + t * 8;

    float4 r0 = *(const float4*)&P[base];
    float4 r1 = *(const float4*)&P[base + 4];
    float v[8] = { r0.x, r0.y, r0.z, r0.w, r1.x, r1.y, r1.z, r1.w };

    float m = -3.0e38f;
    #pragma unroll
    for (int i = 0; i < 8; ++i) m = fmaxf(m, v[i]);
    #pragma unroll
    for (int off = 32; off >= 1; off >>= 1) m = fmaxf(m, __shfl_xor(m, off, 64));
    __shared__ float redm[4];
    if ((t & 63) == 0) redm[t >> 6] = m;
    __syncthreads();
    m = fmaxf(fmaxf(redm[0], redm[1]), fmaxf(redm[2], redm[3]));

    float s = 0.0f;
    #pragma unroll
    for (int i = 0; i < 8; ++i) { v[i] = __expf(v[i] - m); s += v[i]; }
    #pragma unroll
    for (int off = 32; off >= 1; off >>= 1) s += __shfl_xor(s, off, 64);
    __shared__ float reds[4];
    if ((t & 63) == 0) reds[t >> 6] = s;
    __syncthreads();
    s = reds[0] + reds[1] + reds[2] + reds[3];

    const float inv = 1.0f / s;   // s >= 1 always (max element contributes 1)
    r0.x = v[0] * inv; r0.y = v[1] * inv; r0.z = v[2] * inv; r0.w = v[3] * inv;
    r1.x = v[4] * inv; r1.y = v[5] * inv; r1.z = v[6] * inv; r1.w = v[7] * inv;
    *(float4*)&P[base]     = r0;
    *(float4*)&P[base + 4] = r1;

    bf16x8 pb;
    pb[0] = (short)f2bf(r0.x); pb[1] = (short)f2bf(r0.y);
    pb[2] = (short)f2bf(r0.z); pb[3] = (short)f2bf(r0.w);
    pb[4] = (short)f2bf(r1.x); pb[5] = (short)f2bf(r1.y);
    pb[6] = (short)f2bf(r1.z); pb[7] = (short)f2bf(r1.w);
    *(bf16x8*)&Pb[base] = pb;
}

extern "C" void kernel_launch(void* const* d_in, const int* in_sizes, int n_in,
                              void* d_out, int out_size, void* d_ws, size_t ws_size,
                              hipStream_t stream)
{
    (void)in_sizes; (void)n_in; (void)out_size;

    const float* key   = (const float*)d_in[0];
    const float* query = (const float*)d_in[1];
    const int*   mask  = (const int*)d_in[2];
    const float* Wq    = (const float*)d_in[3];
    const float* bq    = (const float*)d_in[4];
    const float* Wk    = (const float*)d_in[5];
    const float* bk    = (const float*)d_in[6];
    const float* Wv    = (const float*)d_in[7];
    const float* bv    = (const float*)d_in[8];

    float* outO = (float*)d_out;                          // [B,LQ,D]  f32
    float* outP = outO + (size_t)BBAT * LQN * DDIM;       // [B,LQ,LK] f32

    // fixed workspace: bf16 weights, 3 x 2 MiB
    unsigned short* Wqb  = (unsigned short*)d_ws;
    unsigned short* Wkb  = Wqb + (size_t)DDIM * DDIM;
    unsigned short* Wvb  = Wkb + (size_t)DDIM * DDIM;
    unsigned short* gbuf = Wvb + (size_t)DDIM * DDIM;

    // per-batch: regionA (qc+kc, later overlaid by Pb) = LQN*LKN shorts (8 MiB)
    //            + Qp + Kp + Vt = 3 * LQN*DDIM shorts (12 MiB)  => 20 MiB
    const size_t fixed = (size_t)3 * DDIM * DDIM * sizeof(unsigned short);
    const size_t perB  = ((size_t)LQN * LKN + (size_t)3 * LQN * DDIM) *
                         sizeof(unsigned short);
    size_t avail = (ws_size > fixed) ? (ws_size - fixed) : 0;
    int g = (int)(avail / perB);
    if (g > BBAT) g = BBAT;
    if (g < 1)    g = 1;

    dim3 blk(256, 1, 1);
    dim3 gblk(512, 1, 1);

    // weights -> bf16 (once)
    cast_bf16<<<dim3(512, 1, 1), blk, 0, stream>>>(Wq, Wqb, (long)DDIM * DDIM / 8);
    cast_bf16<<<dim3(512, 1, 1), blk, 0, stream>>>(Wk, Wkb, (long)DDIM * DDIM / 8);
    cast_bf16<<<dim3(512, 1, 1), blk, 0, stream>>>(Wv, Wvb, (long)DDIM * DDIM / 8);

    for (int b0 = 0; b0 < BBAT; b0 += g) {
        const int gl = (BBAT - b0 < g) ? (BBAT - b0) : g;

        unsigned short* regionA = gbuf;                          // gl * 4Mi shorts
        unsigned short* qc = regionA;                            // [gl*LQ, D] bf16
        unsigned short* kc = regionA + (size_t)gl * LQN * DDIM;  // [gl*LK, D] bf16
        unsigned short* Pb = regionA;                            // [gl,LQ,LK] bf16 (overlays qc/kc)
        unsigned short* Qp = regionA + (size_t)gl * LQN * LKN;   // [gl*LQ, D] bf16
        unsigned short* Kp = Qp + (size_t)gl * LQN * DDIM;       // [gl*LK, D] bf16
        unsigned short* Vt = Kp + (size_t)gl * LKN * DDIM;       // [gl, D, LK] bf16

        // inputs -> bf16
        cast_bf16<<<dim3(2048, 1, 1), blk, 0, stream>>>(
            query + (size_t)b0 * LQN * DDIM, qc, (long)gl * LQN * DDIM / 8);
        cast_bf16<<<dim3(2048, 1, 1), blk, 0, stream>>>(
            key + (size_t)b0 * LKN * DDIM, kc, (long)gl * LKN * DDIM / 8);

        // Qp = qc*Wq^T + bq   (M=gl*2048, N=1024, K=1024)
        gemm_nt<0><<<dim3(4, gl * 8, 1), gblk, 0, stream>>>(qc, Wqb, bq, nullptr, Qp);

        // Kp = kc*Wk^T + bk
        gemm_nt<0><<<dim3(4, gl * 8, 1), gblk, 0, stream>>>(kc, Wkb, bk, nullptr, Kp);

        // Vt[z][d][lk] = Wv*Kp^T + bv   (M=1024, N=gl*2048, K=1024)
        gemm_nt<1><<<dim3(gl * 8, 4, 1), gblk, 0, stream>>>(Wvb, Kp, bv, nullptr, Vt);

        // S[z] = Qp[z]*Kp[z]^T * scale, mask fill  (per z: 2048x2048, K=1024)
        gemm_nt<2><<<dim3(8, 8, gl), gblk, 0, stream>>>(
            Qp, Kp, nullptr, mask + (size_t)b0 * LKN,
            outP + (size_t)b0 * LQN * LKN);

        // softmax rows in place (f32) + bf16 copy for the O-GEMM
        softmax_rows<<<dim3(gl * LQN, 1, 1), blk, 0, stream>>>(
            outP + (size_t)b0 * LQN * LKN, Pb);

        // O[z] = Pb[z]*Vt[z]^T   (per z: M=2048, N=1024, K=2048)
        gemm_nt<3><<<dim3(4, 8, gl), gblk, 0, stream>>>(
            Pb, Vt, nullptr, nullptr, outO + (size_t)b0 * LQN * DDIM);
    }
}